// Round 1
// baseline (774.064 us; speedup 1.0000x reference)
//
#include <hip/hip_runtime.h>

typedef unsigned short u16;
typedef __attribute__((ext_vector_type(8))) short bf8v;
typedef __attribute__((ext_vector_type(4))) float f4v;

#define RRELU_SLOPE 0.22916666667f

__device__ inline float bf2f(u16 u){ unsigned int i = ((unsigned int)u) << 16; float f; __builtin_memcpy(&f, &i, 4); return f; }
__device__ inline u16 f2bf(float f){ unsigned int i; __builtin_memcpy(&i, &f, 4); unsigned int r = (i + 0x7fffu + ((i >> 16) & 1u)) >> 16; return (u16)r; }
__device__ inline float sigm(float x){ return 1.f / (1.f + expf(-x)); }

// ---------------------------------------------------------------- prep: weight casts/transposes
__global__ __launch_bounds__(256) void prep_k(
    const float* __restrict__ Wn, const float* __restrict__ Wl, const float* __restrict__ We,
    const float* __restrict__ wih, const float* __restrict__ whh,
    const float* __restrict__ m1, const float* __restrict__ m2,
    const float* __restrict__ h1, const float* __restrict__ h2,
    const float* __restrict__ attn, const float* __restrict__ alg, const float* __restrict__ rel,
    u16* __restrict__ Bcat, u16* __restrict__ wihb, u16* __restrict__ whhb,
    u16* __restrict__ m1b, u16* __restrict__ m2b, u16* __restrict__ h1b, u16* __restrict__ h2b,
    u16* __restrict__ attnb, u16* __restrict__ algb, u16* __restrict__ relb)
{
    int id = blockIdx.x * 256 + threadIdx.x;
    if (id < 49152) { // Bcat[n*384+k] : n in [0,128), k in [0,384)
        int n = id / 384, k = id % 384;
        float v = (k < 128) ? Wn[k*128 + n] : (k < 256 ? Wl[(k-128)*128 + n] : We[(k-256)*128 + n]);
        Bcat[id] = f2bf(v); return;
    }
    id -= 49152;
    if (id < 49152) { wihb[id] = f2bf(wih[id]); return; } id -= 49152;
    if (id < 49152) { whhb[id] = f2bf(whh[id]); return; } id -= 49152;
    if (id < 32768) { m1b[id]  = f2bf(m1[id]);  return; } id -= 32768;
    if (id < 32768) { m2b[id]  = f2bf(m2[id]);  return; } id -= 32768;
    if (id < 16384) { h1b[id]  = f2bf(h1[id]);  return; } id -= 16384;
    if (id < 16384) { h2b[id]  = f2bf(h2[id]);  return; } id -= 16384;
    if (id < 16384) { attnb[id]= f2bf(attn[id]);return; } id -= 16384;
    if (id < 16384) { algb[id] = f2bf(alg[id]); return; } id -= 16384;
    if (id < 58880) { relb[id] = f2bf(rel[id]); return; }
}

// ---------------------------------------------------------------- edge scatter (atomics)
__global__ __launch_bounds__(256) void edge_scatter_k(
    const int* __restrict__ src, const int* __restrict__ dst, const int* __restrict__ typ,
    const float* __restrict__ h, const float* __restrict__ rel,
    float* __restrict__ ssum, float* __restrict__ deg, int E)
{
    int id = blockIdx.x * 256 + threadIdx.x;
    int e = id >> 7, k = id & 127;
    if (e >= E) return;
    int s = src[e], d = dst[e], t = typ[e];
    float v = h[s*128 + k] + rel[t*128 + k];
    atomicAdd(&ssum[(long)d*128 + k], v);
    if (k == 0) atomicAdd(&deg[d], 1.f);
}

// ---------------------------------------------------------------- build A_cat (20000x384 bf16)
__global__ __launch_bounds__(256) void acat_k(
    const float* __restrict__ ssum, const float* __restrict__ deg, const float* __restrict__ h,
    u16* __restrict__ Acat)
{
    int id = blockIdx.x * 256 + threadIdx.x; // over 20000*128
    int i = id >> 7, k = id & 127;
    float d = deg[i];
    bool has = d > 0.f;
    float nrm = has ? 1.f / d : 0.f;
    float hv = h[id];
    Acat[(long)i*384 + k]       = f2bf(ssum[id] * nrm);
    Acat[(long)i*384 + 128 + k] = has ? f2bf(hv) : (u16)0;
    Acat[(long)i*384 + 256 + k] = has ? (u16)0 : f2bf(hv);
}

// ---------------------------------------------------------------- generic NT bf16 MFMA GEMM
// C[M,N] = A[M,K] @ B[N,K]^T (+bias); epi: 0 plain, 1 rrelu. Optional f32/bf16/transposed-bf16 stores,
// optional residual (v = rscale*v + resid), optional A-row gather.
__global__ __launch_bounds__(256) void gemm_nt(
    const u16* __restrict__ A, const u16* __restrict__ B, const float* __restrict__ bias,
    float* __restrict__ Cf, u16* __restrict__ Cbf, u16* __restrict__ CT,
    const u16* __restrict__ residb, const int* __restrict__ arows,
    int M, int N, int K, int lda, int ldb, int ldc, int ldct, int arow_stride,
    float rscale, int epi)
{
    int tid = threadIdx.x;
    int wave = tid >> 6, lane = tid & 63;
    int ln = lane & 15, q = lane >> 4;
    int bm = blockIdx.y * 64 + wave * 16;
    int bn = blockIdx.x * 64;
    int am = bm + ln; if (am >= M) am = M - 1;
    long ar = arows ? (long)arows[(long)am * arow_stride] : (long)am;
    const u16* Ap = A + ar * lda;
    int br[4];
#pragma unroll
    for (int nt = 0; nt < 4; ++nt) { int n = bn + nt*16 + ln; br[nt] = (n < N) ? n : (N - 1); }
    f4v acc[4] = {};
    for (int kc = 0; kc < K; kc += 32) {
        bf8v af = *(const bf8v*)(Ap + kc + q*8);
#pragma unroll
        for (int nt = 0; nt < 4; ++nt) {
            bf8v bv = *(const bf8v*)(B + (long)br[nt]*ldb + kc + q*8);
            acc[nt] = __builtin_amdgcn_mfma_f32_16x16x32_bf16(af, bv, acc[nt], 0, 0, 0);
        }
    }
#pragma unroll
    for (int nt = 0; nt < 4; ++nt) {
        int n = bn + nt*16 + ln;
        if (n >= N) continue;
        float bv = bias ? bias[n] : 0.f;
#pragma unroll
        for (int r = 0; r < 4; ++r) {
            int m = bm + q*4 + r;
            if (m >= M) continue;
            float v = acc[nt][r] + bv;
            if (epi == 1) v = (v >= 0.f) ? v : v * RRELU_SLOPE;
            if (residb)  v = rscale * v + bf2f(residb[(long)m*ldc + n]);
            long ci = (long)m*ldc + n;
            if (Cf)  Cf[ci]  = v;
            if (Cbf) Cbf[ci] = f2bf(v);
            if (CT)  CT[(long)n*ldct + m] = f2bf(v);
        }
    }
}

// ---------------------------------------------------------------- q_rel gather (also X tail rows)
__global__ __launch_bounds__(256) void qrel_k(
    const u16* __restrict__ mapb, const int* __restrict__ trip,
    u16* __restrict__ qrelb, u16* __restrict__ X)
{
    int id = blockIdx.x * 256 + threadIdx.x; // 1024*128
    int b = id >> 7, k = id & 127;
    int r = trip[b*3 + 1];
    u16 v = mapb[r*128 + k];
    qrelb[id] = v;
    X[(long)(8192 + b)*128 + k] = v;
}

// ---------------------------------------------------------------- masked softmax over 460, bf16 out (padded to 480)
__global__ __launch_bounds__(64) void softmax_k(
    const float* __restrict__ Amat, const float* __restrict__ part, u16* __restrict__ Xattn)
{
    int row = blockIdx.x;            // t*1024 + b
    int t = row >> 10, b = row & 1023;
    int lane = threadIdx.x;
    const float* arow = Amat + (long)b*460;
    const float* crow = part + (long)b*3680 + t*460;
    float v[8], e[8];
    float m = -1e30f;
#pragma unroll
    for (int i = 0; i < 8; ++i) {
        int r = i*64 + lane;
        e[i] = 0.f;
        if (r < 460) {
            float x = crow[r] * arow[r];
            x = (x == 0.f) ? -1e9f : x;
            v[i] = x; m = fmaxf(m, x);
        } else v[i] = -1e30f;
    }
#pragma unroll
    for (int off = 32; off; off >>= 1) m = fmaxf(m, __shfl_xor(m, off));
    float sum = 0.f;
#pragma unroll
    for (int i = 0; i < 8; ++i) {
        int r = i*64 + lane;
        if (r < 460) { e[i] = expf(v[i] - m); sum += e[i]; }
    }
#pragma unroll
    for (int off = 32; off; off >>= 1) sum += __shfl_xor(sum, off);
    float inv = 1.f / sum;
#pragma unroll
    for (int i = 0; i < 8; ++i) {
        int r = i*64 + lane;
        if (r < 460)      Xattn[(long)row*480 + r] = f2bf(e[i] * inv);
        else if (r < 480) Xattn[(long)row*480 + r] = 0;
    }
}

// ---------------------------------------------------------------- GRU scan: 64 blocks x 1 wave, 16 batch rows each
__global__ __launch_bounds__(64) void gru_k(
    const float* __restrict__ gi, const u16* __restrict__ whhb, const float* __restrict__ bhh,
    const float* __restrict__ pred, float* __restrict__ gh2, float* __restrict__ match_acc)
{
    __shared__ u16  hbf[16][128];
    __shared__ float hf [16][128];
    __shared__ float ghl[16][388];
    int lane = threadIdx.x;
    int ln = lane & 15, q = lane >> 4;
    int bb = blockIdx.x * 16;
    for (int i = lane; i < 16*128; i += 64) { hf[i>>7][i&127] = 0.f; hbf[i>>7][i&127] = 0; }
    __syncthreads();
    float msum = 0.f;
    for (int t = 0; t <= 8; ++t) {
        if (t == 8) {
            for (int i = lane; i < 16*128; i += 64) {
                float p = pred[(long)(bb + (i>>7))*128 + (i&127)];
                hf[i>>7][i&127] = p; hbf[i>>7][i&127] = f2bf(p);
            }
            __syncthreads();
        }
        f4v acc[24] = {};
        for (int kc = 0; kc < 128; kc += 32) {
            bf8v af = *(const bf8v*)&hbf[ln][kc + q*8];
#pragma unroll
            for (int nt = 0; nt < 24; ++nt) {
                bf8v bv = *(const bf8v*)(whhb + (long)(nt*16 + ln)*128 + kc + q*8);
                acc[nt] = __builtin_amdgcn_mfma_f32_16x16x32_bf16(af, bv, acc[nt], 0, 0, 0);
            }
        }
#pragma unroll
        for (int nt = 0; nt < 24; ++nt)
#pragma unroll
            for (int r = 0; r < 4; ++r)
                ghl[q*4 + r][nt*16 + ln] = acc[nt][r];
        __syncthreads();
        long girow0 = (t < 8) ? ((long)t*1024 + bb) : (8192 + bb);
        for (int it = 0; it < 32; ++it) {
            int idx = it*64 + lane;
            int m = idx >> 7, k = idx & 127;
            const float* gir = gi + (girow0 + m)*384;
            float rr = sigm(gir[k]       + ghl[m][k]       + bhh[k]);
            float zz = sigm(gir[128 + k] + ghl[m][128 + k] + bhh[128 + k]);
            float nn = tanhf(gir[256 + k] + rr * (ghl[m][256 + k] + bhh[256 + k]));
            float hn = (1.f - zz) * nn + zz * hf[m][k];
            if (t == 7) { float d = pred[(long)(bb + m)*128 + k] - hn; msum += d*d; }
            if (t == 8) { gh2[(long)(bb + m)*128 + k] = hn; }
            else        { hf[m][k] = hn; hbf[m][k] = f2bf(hn); }
        }
        __syncthreads();
    }
    for (int off = 32; off; off >>= 1) msum += __shfl_down(msum, off);
    if (lane == 0) atomicAdd(match_acc, msum);
}

// ---------------------------------------------------------------- V = bf16(SubL * gh2)
__global__ __launch_bounds__(256) void vmul_k(
    const float* __restrict__ subl, const float* __restrict__ gh2, u16* __restrict__ V)
{
    int id = blockIdx.x * 256 + threadIdx.x;
    V[id] = f2bf(subl[id] * gh2[id]);
}

// ---------------------------------------------------------------- score GEMM: sigmoid store + softplus reduce
__global__ __launch_bounds__(256) void score_k(
    const u16* __restrict__ V, const u16* __restrict__ AL,
    float* __restrict__ out, float* __restrict__ sp_acc, int N)
{
    int tid = threadIdx.x;
    int wave = tid >> 6, lane = tid & 63;
    int ln = lane & 15, q = lane >> 4;
    int bm = blockIdx.y * 64 + wave * 16;
    int bn = blockIdx.x * 64;
    const u16* Ap = V + (long)(bm + ln)*128;
    int br[4];
#pragma unroll
    for (int nt = 0; nt < 4; ++nt) { int n = bn + nt*16 + ln; br[nt] = (n < N) ? n : (N - 1); }
    f4v acc[4] = {};
    for (int kc = 0; kc < 128; kc += 32) {
        bf8v af = *(const bf8v*)(Ap + kc + q*8);
#pragma unroll
        for (int nt = 0; nt < 4; ++nt) {
            bf8v bv = *(const bf8v*)(AL + (long)br[nt]*128 + kc + q*8);
            acc[nt] = __builtin_amdgcn_mfma_f32_16x16x32_bf16(af, bv, acc[nt], 0, 0, 0);
        }
    }
    float lsum = 0.f;
#pragma unroll
    for (int nt = 0; nt < 4; ++nt) {
        int n = bn + nt*16 + ln;
        if (n >= N) continue;
#pragma unroll
        for (int r = 0; r < 4; ++r) {
            int m = bm + q*4 + r;
            float s = acc[nt][r];
            out[(long)m*N + n] = 1.f / (1.f + expf(-s));
            lsum += fmaxf(s, 0.f) + log1pf(expf(-fabsf(s)));
        }
    }
#pragma unroll
    for (int off = 32; off; off >>= 1) lsum += __shfl_xor(lsum, off);
    __shared__ float red[4];
    if (lane == 0) red[wave] = lsum;
    __syncthreads();
    if (tid == 0) atomicAdd(sp_acc, red[0] + red[1] + red[2] + red[3]);
}

// ---------------------------------------------------------------- per-b score_[b, obj_b], accumulate -s
__global__ __launch_bounds__(64) void objdot_k(
    const u16* __restrict__ V, const u16* __restrict__ AL, const int* __restrict__ trip,
    float* __restrict__ obj_acc)
{
    int b = blockIdx.x, lane = threadIdx.x;
    int obj = trip[b*3 + 2];
    const u16* v = V + (long)b*128;
    const u16* a = AL + (long)obj*128;
    float s = 0.f;
    for (int k = lane; k < 128; k += 64) s += bf2f(v[k]) * bf2f(a[k]);
    for (int off = 32; off; off >>= 1) s += __shfl_down(s, off);
    if (lane == 0) atomicAdd(obj_acc, -s);
}

// ---------------------------------------------------------------- finalize scalars
__global__ void final_k(const float* __restrict__ acc, float* __restrict__ out)
{
    out[20480000] = acc[0] / (1024.f * 128.f);
    out[20480001] = (acc[1] + acc[2]) / (1024.f * 20000.f);
}

// ================================================================ host
extern "C" void kernel_launch(void* const* d_in, const int* in_sizes, int n_in,
                              void* d_out, int out_size, void* d_ws, size_t ws_size,
                              hipStream_t stream)
{
    const float* ent  = (const float*)d_in[0];
    const float* rel  = (const float*)d_in[1];
    const float* Wn   = (const float*)d_in[2];
    const float* Wl   = (const float*)d_in[3];
    const float* We   = (const float*)d_in[4];
    const float* wih  = (const float*)d_in[5];
    const float* whh  = (const float*)d_in[6];
    const float* b_ih = (const float*)d_in[7];
    const float* b_hh = (const float*)d_in[8];
    const float* Wm1  = (const float*)d_in[9];
    const float* bm1  = (const float*)d_in[10];
    const float* Wm2  = (const float*)d_in[11];
    const float* bm2  = (const float*)d_in[12];
    const float* Wh1  = (const float*)d_in[13];
    const float* bh1  = (const float*)d_in[14];
    const float* Wh2  = (const float*)d_in[15];
    const float* bh2  = (const float*)d_in[16];
    const float* Wal  = (const float*)d_in[17];
    const float* bal  = (const float*)d_in[18];
    const float* Wat  = (const float*)d_in[19];
    const float* bat  = (const float*)d_in[20];
    const float* part = (const float*)d_in[21];
    const int* esrc   = (const int*)d_in[22];
    const int* edst   = (const int*)d_in[23];
    const int* etyp   = (const int*)d_in[24];
    const int* trip   = (const int*)d_in[25];
    float* out = (float*)d_out;

    char* ws = (char*)d_ws;
    size_t off = 0;
    auto alloc = [&](size_t bytes) { size_t o = off; off = (off + bytes + 255) & ~(size_t)255; return o; };

    // zeroed region first (one memset)
    size_t o_acc   = alloc(256);                  // [0]=match [1]=softplus [2]=obj
    size_t o_deg   = alloc(20000 * 4);
    size_t o_ssum  = alloc((size_t)20000 * 128 * 4);
    size_t o_mapT  = alloc(128 * 480 * 2);
    size_t zend = off;
    // non-zeroed
    size_t o_acat  = alloc((size_t)20000 * 384 * 2);
    size_t o_pre   = alloc((size_t)20000 * 128 * 2);
    size_t o_aln   = alloc((size_t)20000 * 128 * 2);
    size_t o_bcat  = alloc(128 * 384 * 2);
    size_t o_wih   = alloc(384 * 128 * 2);
    size_t o_whh   = alloc(384 * 128 * 2);
    size_t o_m1    = alloc(256 * 128 * 2);
    size_t o_m2    = alloc(128 * 256 * 2);
    size_t o_h1    = alloc(128 * 128 * 2);
    size_t o_h2    = alloc(128 * 128 * 2);
    size_t o_at    = alloc(128 * 128 * 2);
    size_t o_al    = alloc(128 * 128 * 2);
    size_t o_rel   = alloc(460 * 128 * 2);
    size_t o_t1    = alloc(460 * 256 * 2);
    size_t o_map   = alloc(460 * 128 * 2);
    size_t o_qrel  = alloc(1024 * 128 * 2);
    size_t o_atq   = alloc(1024 * 128 * 2);
    size_t o_th1   = alloc(1024 * 128 * 2);
    size_t o_pred  = alloc(1024 * 128 * 4);
    size_t o_amat  = alloc((size_t)1024 * 460 * 4);
    size_t o_xat   = alloc((size_t)8192 * 480 * 2);
    size_t o_X     = alloc((size_t)9216 * 128 * 2);
    size_t o_gi    = alloc((size_t)9216 * 384 * 4);
    size_t o_subl  = alloc(1024 * 128 * 4);
    size_t o_gh2   = alloc(1024 * 128 * 4);
    size_t o_V     = alloc(1024 * 128 * 2);

    float* accp  = (float*)(ws + o_acc);
    float* degp  = (float*)(ws + o_deg);
    float* ssum  = (float*)(ws + o_ssum);
    u16* mapT    = (u16*)(ws + o_mapT);
    u16* acat    = (u16*)(ws + o_acat);
    u16* preb    = (u16*)(ws + o_pre);
    u16* alnb    = (u16*)(ws + o_aln);
    u16* bcat    = (u16*)(ws + o_bcat);
    u16* wihb    = (u16*)(ws + o_wih);
    u16* whhb    = (u16*)(ws + o_whh);
    u16* m1b     = (u16*)(ws + o_m1);
    u16* m2b     = (u16*)(ws + o_m2);
    u16* h1b     = (u16*)(ws + o_h1);
    u16* h2b     = (u16*)(ws + o_h2);
    u16* atb     = (u16*)(ws + o_at);
    u16* alb     = (u16*)(ws + o_al);
    u16* relb    = (u16*)(ws + o_rel);
    u16* t1b     = (u16*)(ws + o_t1);
    u16* mapb    = (u16*)(ws + o_map);
    u16* qrelb   = (u16*)(ws + o_qrel);
    u16* atqb    = (u16*)(ws + o_atq);
    u16* th1b    = (u16*)(ws + o_th1);
    float* predf = (float*)(ws + o_pred);
    float* amat  = (float*)(ws + o_amat);
    u16* xat     = (u16*)(ws + o_xat);
    u16* Xb      = (u16*)(ws + o_X);
    float* gif   = (float*)(ws + o_gi);
    float* subl  = (float*)(ws + o_subl);
    float* gh2f  = (float*)(ws + o_gh2);
    u16* Vb      = (u16*)(ws + o_V);

    hipMemsetAsync(ws, 0, zend, stream);

    prep_k<<<1318, 256, 0, stream>>>(Wn, Wl, We, wih, whh, Wm1, Wm2, Wh1, Wh2, Wat, Wal, rel,
                                     bcat, wihb, whhb, m1b, m2b, h1b, h2b, atb, alb, relb);

    edge_scatter_k<<<200000, 256, 0, stream>>>(esrc, edst, etyp, ent, rel, ssum, degp, 400000);

    acat_k<<<10000, 256, 0, stream>>>(ssum, degp, ent, acat);

    // pre_emb = rrelu(A_cat @ Bcat^T)  [20000 x 128]
    gemm_nt<<<dim3(2, 313), 256, 0, stream>>>(acat, bcat, nullptr, nullptr, preb, nullptr, nullptr, nullptr,
                                              20000, 128, 384, 384, 384, 128, 0, 0, 0.f, 1);
    // aligned_all = pre_emb @ W_align^T + b_align
    gemm_nt<<<dim3(2, 313), 256, 0, stream>>>(preb, alb, bal, nullptr, alnb, nullptr, nullptr, nullptr,
                                              20000, 128, 128, 128, 128, 128, 0, 0, 0.f, 0);
    // t1 = rel_emb @ W_map1^T + b_map1  [460 x 256]
    gemm_nt<<<dim3(4, 8), 256, 0, stream>>>(relb, m1b, bm1, nullptr, t1b, nullptr, nullptr, nullptr,
                                            460, 256, 128, 128, 128, 256, 0, 0, 0.f, 0);
    // mapped_rel = t1 @ W_map2^T + b_map2  [460 x 128] (+ transposed copy, ldct=480)
    gemm_nt<<<dim3(2, 8), 256, 0, stream>>>(t1b, m2b, bm2, nullptr, mapb, mapT, nullptr, nullptr,
                                            460, 128, 256, 256, 256, 128, 480, 0, 0.f, 0);

    qrel_k<<<512, 256, 0, stream>>>(mapb, trip, qrelb, Xb);

    // attnq = q_rel @ W_attn^T + b_attn
    gemm_nt<<<dim3(2, 16), 256, 0, stream>>>(qrelb, atb, bat, nullptr, atqb, nullptr, nullptr, nullptr,
                                             1024, 128, 128, 128, 128, 128, 0, 0, 0.f, 0);
    // th1 = q_rel @ W_h1^T + b_h1
    gemm_nt<<<dim3(2, 16), 256, 0, stream>>>(qrelb, h1b, bh1, nullptr, th1b, nullptr, nullptr, nullptr,
                                             1024, 128, 128, 128, 128, 128, 0, 0, 0.f, 0);
    // predicted_hist = 0.1*(th1 @ W_h2^T + b_h2) + q_rel   (f32)
    gemm_nt<<<dim3(2, 16), 256, 0, stream>>>(th1b, h2b, bh2, predf, nullptr, nullptr, qrelb, nullptr,
                                             1024, 128, 128, 128, 128, 128, 0, 0, 0.1f, 0);
    // A = attnq @ mapped_rel^T  [1024 x 460] (f32)
    gemm_nt<<<dim3(8, 16), 256, 0, stream>>>(atqb, mapb, nullptr, amat, nullptr, nullptr, nullptr, nullptr,
                                             1024, 460, 128, 128, 128, 460, 0, 0, 0.f, 0);

    softmax_k<<<8192, 64, 0, stream>>>(amat, part, xat);

    // rel_path = attn @ mapped_rel  [8192 x 128] -> X rows 0..8191 (bf16)
    gemm_nt<<<dim3(2, 128), 256, 0, stream>>>(xat, mapT, nullptr, nullptr, Xb, nullptr, nullptr, nullptr,
                                              8192, 128, 480, 480, 480, 128, 0, 0, 0.f, 0);
    // gi = X @ w_ih^T + b_ih  [9216 x 384] (f32)
    gemm_nt<<<dim3(6, 144), 256, 0, stream>>>(Xb, wihb, b_ih, gif, nullptr, nullptr, nullptr, nullptr,
                                              9216, 384, 128, 128, 128, 384, 0, 0, 0.f, 0);
    // SubL = pre_emb[triples[:,0]] @ W_align^T + b_align  (f32)
    gemm_nt<<<dim3(2, 16), 256, 0, stream>>>(preb, alb, bal, subl, nullptr, nullptr, nullptr, trip,
                                             1024, 128, 128, 128, 128, 128, 0, 3, 0.f, 0);

    gru_k<<<64, 64, 0, stream>>>(gif, whhb, b_hh, predf, gh2f, accp + 0);

    vmul_k<<<512, 256, 0, stream>>>(subl, gh2f, Vb);

    score_k<<<dim3(313, 16), 256, 0, stream>>>(Vb, alnb, out, accp + 1, 20000);

    objdot_k<<<1024, 64, 0, stream>>>(Vb, alnb, trip, accp + 2);

    final_k<<<1, 1, 0, stream>>>(accp, out);

    (void)in_sizes; (void)n_in; (void)out_size; (void)ws_size;
}

// Round 2
// 701.303 us; speedup vs baseline: 1.1038x; 1.1038x over previous
//
#include <hip/hip_runtime.h>

typedef unsigned short u16;
typedef __attribute__((ext_vector_type(8))) short bf8v;
typedef __attribute__((ext_vector_type(4))) float f4v;

#define RRELU_SLOPE 0.22916666667f

__device__ inline float bf2f(u16 u){ unsigned int i = ((unsigned int)u) << 16; float f; __builtin_memcpy(&f, &i, 4); return f; }
__device__ inline u16 f2bf(float f){ unsigned int i; __builtin_memcpy(&i, &f, 4); unsigned int r = (i + 0x7fffu + ((i >> 16) & 1u)) >> 16; return (u16)r; }
__device__ inline float sigm(float x){ return 1.f / (1.f + expf(-x)); }

// ---------------------------------------------------------------- prep: weight casts/transposes
__global__ __launch_bounds__(256) void prep_k(
    const float* __restrict__ Wn, const float* __restrict__ Wl, const float* __restrict__ We,
    const float* __restrict__ wih, const float* __restrict__ whh,
    const float* __restrict__ m1, const float* __restrict__ m2,
    const float* __restrict__ h1, const float* __restrict__ h2,
    const float* __restrict__ attn, const float* __restrict__ alg, const float* __restrict__ rel,
    u16* __restrict__ Bcat, u16* __restrict__ wihb, u16* __restrict__ whhb,
    u16* __restrict__ m1b, u16* __restrict__ m2b, u16* __restrict__ h1b, u16* __restrict__ h2b,
    u16* __restrict__ attnb, u16* __restrict__ algb, u16* __restrict__ relb)
{
    int id = blockIdx.x * 256 + threadIdx.x;
    if (id < 49152) { // Bcat[n*384+k] : n in [0,128), k in [0,384)
        int n = id / 384, k = id % 384;
        float v = (k < 128) ? Wn[k*128 + n] : (k < 256 ? Wl[(k-128)*128 + n] : We[(k-256)*128 + n]);
        Bcat[id] = f2bf(v); return;
    }
    id -= 49152;
    if (id < 49152) { wihb[id] = f2bf(wih[id]); return; } id -= 49152;
    if (id < 49152) { whhb[id] = f2bf(whh[id]); return; } id -= 49152;
    if (id < 32768) { m1b[id]  = f2bf(m1[id]);  return; } id -= 32768;
    if (id < 32768) { m2b[id]  = f2bf(m2[id]);  return; } id -= 32768;
    if (id < 16384) { h1b[id]  = f2bf(h1[id]);  return; } id -= 16384;
    if (id < 16384) { h2b[id]  = f2bf(h2[id]);  return; } id -= 16384;
    if (id < 16384) { attnb[id]= f2bf(attn[id]);return; } id -= 16384;
    if (id < 16384) { algb[id] = f2bf(alg[id]); return; } id -= 16384;
    if (id < 58880) { relb[id] = f2bf(rel[id]); return; }
}

// ---------------------------------------------------------------- edge histogram (int atomics, 1 per edge)
__global__ __launch_bounds__(256) void hist_k(
    const int* __restrict__ dst, int* __restrict__ hist, int E)
{
    int e = blockIdx.x * 256 + threadIdx.x;
    if (e < E) atomicAdd(&hist[dst[e]], 1);
}

// ---------------------------------------------------------------- exclusive scan over 20000 bins (1 block)
__global__ __launch_bounds__(1024) void scan_k(
    const int* __restrict__ hist, int* __restrict__ starts, int* __restrict__ cursor)
{
    __shared__ int part[1024];
    int t = threadIdx.x;
    int base = t * 20;
    int s = 0;
    for (int j = 0; j < 20; ++j) { int idx = base + j; if (idx < 20000) s += hist[idx]; }
    part[t] = s;
    __syncthreads();
    for (int off = 1; off < 1024; off <<= 1) {
        int v = (t >= off) ? part[t - off] : 0;
        __syncthreads();
        part[t] += v;
        __syncthreads();
    }
    int run = (t > 0) ? part[t - 1] : 0;
    for (int j = 0; j < 20; ++j) {
        int idx = base + j;
        if (idx < 20000) { starts[idx] = run; cursor[idx] = run; run += hist[idx]; }
    }
    if (t == 1023) starts[20000] = run;
}

// ---------------------------------------------------------------- scatter edges into CSR order (packed src,typ)
__global__ __launch_bounds__(256) void scatter_k(
    const int* __restrict__ src, const int* __restrict__ dst, const int* __restrict__ typ,
    int* __restrict__ cursor, int2* __restrict__ spack, int E)
{
    int e = blockIdx.x * 256 + threadIdx.x;
    if (e >= E) return;
    int d = dst[e];
    int p = atomicAdd(&cursor[d], 1);
    spack[p] = make_int2(src[e], typ[e]);
}

// ---------------------------------------------------------------- segmented sum + fused A_cat build
__global__ __launch_bounds__(128) void agg_acat_k(
    const int2* __restrict__ spack, const int* __restrict__ starts,
    const float* __restrict__ h, const float* __restrict__ rel, u16* __restrict__ Acat)
{
    int i = blockIdx.x;           // dst entity
    int k = threadIdx.x;          // feature
    int s0 = starts[i], s1 = starts[i + 1];
    float sum = 0.f;
    for (int e = s0; e < s1; ++e) {
        int2 st = spack[e];
        sum += h[(long)st.x * 128 + k] + rel[(long)st.y * 128 + k];
    }
    bool has = s1 > s0;
    float nrm = has ? 1.f / (float)(s1 - s0) : 0.f;
    float hv = h[(long)i * 128 + k];
    long o = (long)i * 384 + k;
    Acat[o]       = f2bf(sum * nrm);
    Acat[o + 128] = has ? f2bf(hv) : (u16)0;
    Acat[o + 256] = has ? (u16)0 : f2bf(hv);
}

// ---------------------------------------------------------------- generic NT bf16 MFMA GEMM
__global__ __launch_bounds__(256) void gemm_nt(
    const u16* __restrict__ A, const u16* __restrict__ B, const float* __restrict__ bias,
    float* __restrict__ Cf, u16* __restrict__ Cbf, u16* __restrict__ CT,
    const u16* __restrict__ residb, const int* __restrict__ arows,
    int M, int N, int K, int lda, int ldb, int ldc, int ldct, int arow_stride,
    float rscale, int epi)
{
    int tid = threadIdx.x;
    int wave = tid >> 6, lane = tid & 63;
    int ln = lane & 15, q = lane >> 4;
    int bm = blockIdx.y * 64 + wave * 16;
    int bn = blockIdx.x * 64;
    int am = bm + ln; if (am >= M) am = M - 1;
    long ar = arows ? (long)arows[(long)am * arow_stride] : (long)am;
    const u16* Ap = A + ar * lda;
    int br[4];
#pragma unroll
    for (int nt = 0; nt < 4; ++nt) { int n = bn + nt*16 + ln; br[nt] = (n < N) ? n : (N - 1); }
    f4v acc[4] = {};
    for (int kc = 0; kc < K; kc += 32) {
        bf8v af = *(const bf8v*)(Ap + kc + q*8);
#pragma unroll
        for (int nt = 0; nt < 4; ++nt) {
            bf8v bv = *(const bf8v*)(B + (long)br[nt]*ldb + kc + q*8);
            acc[nt] = __builtin_amdgcn_mfma_f32_16x16x32_bf16(af, bv, acc[nt], 0, 0, 0);
        }
    }
#pragma unroll
    for (int nt = 0; nt < 4; ++nt) {
        int n = bn + nt*16 + ln;
        if (n >= N) continue;
        float bv = bias ? bias[n] : 0.f;
#pragma unroll
        for (int r = 0; r < 4; ++r) {
            int m = bm + q*4 + r;
            if (m >= M) continue;
            float v = acc[nt][r] + bv;
            if (epi == 1) v = (v >= 0.f) ? v : v * RRELU_SLOPE;
            if (residb)  v = rscale * v + bf2f(residb[(long)m*ldc + n]);
            long ci = (long)m*ldc + n;
            if (Cf)  Cf[ci]  = v;
            if (Cbf) Cbf[ci] = f2bf(v);
            if (CT)  CT[(long)n*ldct + m] = f2bf(v);
        }
    }
}

// ---------------------------------------------------------------- q_rel gather (also X tail rows)
__global__ __launch_bounds__(256) void qrel_k(
    const u16* __restrict__ mapb, const int* __restrict__ trip,
    u16* __restrict__ qrelb, u16* __restrict__ X)
{
    int id = blockIdx.x * 256 + threadIdx.x; // 1024*128
    int b = id >> 7, k = id & 127;
    int r = trip[b*3 + 1];
    u16 v = mapb[r*128 + k];
    qrelb[id] = v;
    X[(long)(8192 + b)*128 + k] = v;
}

// ---------------------------------------------------------------- masked softmax over 460, bf16 out (padded to 480)
__global__ __launch_bounds__(64) void softmax_k(
    const float* __restrict__ Amat, const float* __restrict__ part, u16* __restrict__ Xattn)
{
    int row = blockIdx.x;            // t*1024 + b
    int t = row >> 10, b = row & 1023;
    int lane = threadIdx.x;
    const float* arow = Amat + (long)b*460;
    const float* crow = part + (long)b*3680 + t*460;
    float v[8], e[8];
    float m = -1e30f;
#pragma unroll
    for (int i = 0; i < 8; ++i) {
        int r = i*64 + lane;
        e[i] = 0.f;
        if (r < 460) {
            float x = crow[r] * arow[r];
            x = (x == 0.f) ? -1e9f : x;
            v[i] = x; m = fmaxf(m, x);
        } else v[i] = -1e30f;
    }
#pragma unroll
    for (int off = 32; off; off >>= 1) m = fmaxf(m, __shfl_xor(m, off));
    float sum = 0.f;
#pragma unroll
    for (int i = 0; i < 8; ++i) {
        int r = i*64 + lane;
        if (r < 460) { e[i] = expf(v[i] - m); sum += e[i]; }
    }
#pragma unroll
    for (int off = 32; off; off >>= 1) sum += __shfl_xor(sum, off);
    float inv = 1.f / sum;
#pragma unroll
    for (int i = 0; i < 8; ++i) {
        int r = i*64 + lane;
        if (r < 460)      Xattn[(long)row*480 + r] = f2bf(e[i] * inv);
        else if (r < 480) Xattn[(long)row*480 + r] = 0;
    }
}

// ---------------------------------------------------------------- GRU scan: 64 blocks x 1 wave, 16 batch rows each
__global__ __launch_bounds__(64) void gru_k(
    const float* __restrict__ gi, const u16* __restrict__ whhb, const float* __restrict__ bhh,
    const float* __restrict__ pred, float* __restrict__ gh2, float* __restrict__ match_acc)
{
    __shared__ u16  hbf[16][128];
    __shared__ float hf [16][128];
    __shared__ float ghl[16][388];
    int lane = threadIdx.x;
    int ln = lane & 15, q = lane >> 4;
    int bb = blockIdx.x * 16;
    for (int i = lane; i < 16*128; i += 64) { hf[i>>7][i&127] = 0.f; hbf[i>>7][i&127] = 0; }
    __syncthreads();
    float msum = 0.f;
    for (int t = 0; t <= 8; ++t) {
        if (t == 8) {
            for (int i = lane; i < 16*128; i += 64) {
                float p = pred[(long)(bb + (i>>7))*128 + (i&127)];
                hf[i>>7][i&127] = p; hbf[i>>7][i&127] = f2bf(p);
            }
            __syncthreads();
        }
        f4v acc[24] = {};
        for (int kc = 0; kc < 128; kc += 32) {
            bf8v af = *(const bf8v*)&hbf[ln][kc + q*8];
#pragma unroll
            for (int nt = 0; nt < 24; ++nt) {
                bf8v bv = *(const bf8v*)(whhb + (long)(nt*16 + ln)*128 + kc + q*8);
                acc[nt] = __builtin_amdgcn_mfma_f32_16x16x32_bf16(af, bv, acc[nt], 0, 0, 0);
            }
        }
#pragma unroll
        for (int nt = 0; nt < 24; ++nt)
#pragma unroll
            for (int r = 0; r < 4; ++r)
                ghl[q*4 + r][nt*16 + ln] = acc[nt][r];
        __syncthreads();
        long girow0 = (t < 8) ? ((long)t*1024 + bb) : (8192 + bb);
        for (int it = 0; it < 32; ++it) {
            int idx = it*64 + lane;
            int m = idx >> 7, k = idx & 127;
            const float* gir = gi + (girow0 + m)*384;
            float rr = sigm(gir[k]       + ghl[m][k]       + bhh[k]);
            float zz = sigm(gir[128 + k] + ghl[m][128 + k] + bhh[128 + k]);
            float nn = tanhf(gir[256 + k] + rr * (ghl[m][256 + k] + bhh[256 + k]));
            float hn = (1.f - zz) * nn + zz * hf[m][k];
            if (t == 7) { float d = pred[(long)(bb + m)*128 + k] - hn; msum += d*d; }
            if (t == 8) { gh2[(long)(bb + m)*128 + k] = hn; }
            else        { hf[m][k] = hn; hbf[m][k] = f2bf(hn); }
        }
        __syncthreads();
    }
    for (int off = 32; off; off >>= 1) msum += __shfl_down(msum, off);
    if (lane == 0) atomicAdd(match_acc, msum);
}

// ---------------------------------------------------------------- V = bf16(SubL * gh2)
__global__ __launch_bounds__(256) void vmul_k(
    const float* __restrict__ subl, const float* __restrict__ gh2, u16* __restrict__ V)
{
    int id = blockIdx.x * 256 + threadIdx.x;
    V[id] = f2bf(subl[id] * gh2[id]);
}

// ---------------------------------------------------------------- score GEMM: sigmoid store + softplus reduce
__global__ __launch_bounds__(256) void score_k(
    const u16* __restrict__ V, const u16* __restrict__ AL,
    float* __restrict__ out, float* __restrict__ sp_acc, int N)
{
    int tid = threadIdx.x;
    int wave = tid >> 6, lane = tid & 63;
    int ln = lane & 15, q = lane >> 4;
    int bm = blockIdx.y * 64 + wave * 16;
    int bn = blockIdx.x * 64;
    const u16* Ap = V + (long)(bm + ln)*128;
    int br[4];
#pragma unroll
    for (int nt = 0; nt < 4; ++nt) { int n = bn + nt*16 + ln; br[nt] = (n < N) ? n : (N - 1); }
    f4v acc[4] = {};
    for (int kc = 0; kc < 128; kc += 32) {
        bf8v af = *(const bf8v*)(Ap + kc + q*8);
#pragma unroll
        for (int nt = 0; nt < 4; ++nt) {
            bf8v bv = *(const bf8v*)(AL + (long)br[nt]*128 + kc + q*8);
            acc[nt] = __builtin_amdgcn_mfma_f32_16x16x32_bf16(af, bv, acc[nt], 0, 0, 0);
        }
    }
    float lsum = 0.f;
#pragma unroll
    for (int nt = 0; nt < 4; ++nt) {
        int n = bn + nt*16 + ln;
        if (n >= N) continue;
#pragma unroll
        for (int r = 0; r < 4; ++r) {
            int m = bm + q*4 + r;
            float s = acc[nt][r];
            out[(long)m*N + n] = 1.f / (1.f + expf(-s));
            lsum += fmaxf(s, 0.f) + log1pf(expf(-fabsf(s)));
        }
    }
#pragma unroll
    for (int off = 32; off; off >>= 1) lsum += __shfl_xor(lsum, off);
    __shared__ float red[4];
    if (lane == 0) red[wave] = lsum;
    __syncthreads();
    if (tid == 0) atomicAdd(sp_acc, red[0] + red[1] + red[2] + red[3]);
}

// ---------------------------------------------------------------- per-b score_[b, obj_b], accumulate -s
__global__ __launch_bounds__(64) void objdot_k(
    const u16* __restrict__ V, const u16* __restrict__ AL, const int* __restrict__ trip,
    float* __restrict__ obj_acc)
{
    int b = blockIdx.x, lane = threadIdx.x;
    int obj = trip[b*3 + 2];
    const u16* v = V + (long)b*128;
    const u16* a = AL + (long)obj*128;
    float s = 0.f;
    for (int k = lane; k < 128; k += 64) s += bf2f(v[k]) * bf2f(a[k]);
    for (int off = 32; off; off >>= 1) s += __shfl_down(s, off);
    if (lane == 0) atomicAdd(obj_acc, -s);
}

// ---------------------------------------------------------------- finalize scalars
__global__ void final_k(const float* __restrict__ acc, float* __restrict__ out)
{
    out[20480000] = acc[0] / (1024.f * 128.f);
    out[20480001] = (acc[1] + acc[2]) / (1024.f * 20000.f);
}

// ================================================================ host
extern "C" void kernel_launch(void* const* d_in, const int* in_sizes, int n_in,
                              void* d_out, int out_size, void* d_ws, size_t ws_size,
                              hipStream_t stream)
{
    const float* ent  = (const float*)d_in[0];
    const float* rel  = (const float*)d_in[1];
    const float* Wn   = (const float*)d_in[2];
    const float* Wl   = (const float*)d_in[3];
    const float* We   = (const float*)d_in[4];
    const float* wih  = (const float*)d_in[5];
    const float* whh  = (const float*)d_in[6];
    const float* b_ih = (const float*)d_in[7];
    const float* b_hh = (const float*)d_in[8];
    const float* Wm1  = (const float*)d_in[9];
    const float* bm1  = (const float*)d_in[10];
    const float* Wm2  = (const float*)d_in[11];
    const float* bm2  = (const float*)d_in[12];
    const float* Wh1  = (const float*)d_in[13];
    const float* bh1  = (const float*)d_in[14];
    const float* Wh2  = (const float*)d_in[15];
    const float* bh2  = (const float*)d_in[16];
    const float* Wal  = (const float*)d_in[17];
    const float* bal  = (const float*)d_in[18];
    const float* Wat  = (const float*)d_in[19];
    const float* bat  = (const float*)d_in[20];
    const float* part = (const float*)d_in[21];
    const int* esrc   = (const int*)d_in[22];
    const int* edst   = (const int*)d_in[23];
    const int* etyp   = (const int*)d_in[24];
    const int* trip   = (const int*)d_in[25];
    float* out = (float*)d_out;
    const int E = in_sizes[22];

    char* ws = (char*)d_ws;
    size_t off = 0;
    auto alloc = [&](size_t bytes) { size_t o = off; off = (off + bytes + 255) & ~(size_t)255; return o; };

    // zeroed region first (one memset)
    size_t o_acc   = alloc(256);                  // [0]=match [1]=softplus [2]=obj
    size_t o_hist  = alloc(20000 * 4);
    size_t o_mapT  = alloc(128 * 480 * 2);
    size_t zend = off;
    // non-zeroed
    size_t o_starts= alloc(20004 * 4);
    size_t o_cur   = alloc(20000 * 4);
    size_t o_spack = alloc((size_t)E * 8);
    size_t o_acat  = alloc((size_t)20000 * 384 * 2);
    size_t o_pre   = alloc((size_t)20000 * 128 * 2);
    size_t o_aln   = alloc((size_t)20000 * 128 * 2);
    size_t o_bcat  = alloc(128 * 384 * 2);
    size_t o_wih   = alloc(384 * 128 * 2);
    size_t o_whh   = alloc(384 * 128 * 2);
    size_t o_m1    = alloc(256 * 128 * 2);
    size_t o_m2    = alloc(128 * 256 * 2);
    size_t o_h1    = alloc(128 * 128 * 2);
    size_t o_h2    = alloc(128 * 128 * 2);
    size_t o_at    = alloc(128 * 128 * 2);
    size_t o_al    = alloc(128 * 128 * 2);
    size_t o_rel   = alloc(460 * 128 * 2);
    size_t o_t1    = alloc(460 * 256 * 2);
    size_t o_map   = alloc(460 * 128 * 2);
    size_t o_qrel  = alloc(1024 * 128 * 2);
    size_t o_atq   = alloc(1024 * 128 * 2);
    size_t o_th1   = alloc(1024 * 128 * 2);
    size_t o_pred  = alloc(1024 * 128 * 4);
    size_t o_amat  = alloc((size_t)1024 * 460 * 4);
    size_t o_xat   = alloc((size_t)8192 * 480 * 2);
    size_t o_X     = alloc((size_t)9216 * 128 * 2);
    size_t o_gi    = alloc((size_t)9216 * 384 * 4);
    size_t o_subl  = alloc(1024 * 128 * 4);
    size_t o_gh2   = alloc(1024 * 128 * 4);
    size_t o_V     = alloc(1024 * 128 * 2);

    float* accp  = (float*)(ws + o_acc);
    int* histp   = (int*)(ws + o_hist);
    u16* mapT    = (u16*)(ws + o_mapT);
    int* startsp = (int*)(ws + o_starts);
    int* curp    = (int*)(ws + o_cur);
    int2* spack  = (int2*)(ws + o_spack);
    u16* acat    = (u16*)(ws + o_acat);
    u16* preb    = (u16*)(ws + o_pre);
    u16* alnb    = (u16*)(ws + o_aln);
    u16* bcat    = (u16*)(ws + o_bcat);
    u16* wihb    = (u16*)(ws + o_wih);
    u16* whhb    = (u16*)(ws + o_whh);
    u16* m1b     = (u16*)(ws + o_m1);
    u16* m2b     = (u16*)(ws + o_m2);
    u16* h1b     = (u16*)(ws + o_h1);
    u16* h2b     = (u16*)(ws + o_h2);
    u16* atb     = (u16*)(ws + o_at);
    u16* alb     = (u16*)(ws + o_al);
    u16* relb    = (u16*)(ws + o_rel);
    u16* t1b     = (u16*)(ws + o_t1);
    u16* mapb    = (u16*)(ws + o_map);
    u16* qrelb   = (u16*)(ws + o_qrel);
    u16* atqb    = (u16*)(ws + o_atq);
    u16* th1b    = (u16*)(ws + o_th1);
    float* predf = (float*)(ws + o_pred);
    float* amat  = (float*)(ws + o_amat);
    u16* xat     = (u16*)(ws + o_xat);
    u16* Xb      = (u16*)(ws + o_X);
    float* gif   = (float*)(ws + o_gi);
    float* subl  = (float*)(ws + o_subl);
    float* gh2f  = (float*)(ws + o_gh2);
    u16* Vb      = (u16*)(ws + o_V);

    hipMemsetAsync(ws, 0, zend, stream);

    prep_k<<<1318, 256, 0, stream>>>(Wn, Wl, We, wih, whh, Wm1, Wm2, Wh1, Wh2, Wat, Wal, rel,
                                     bcat, wihb, whhb, m1b, m2b, h1b, h2b, atb, alb, relb);

    // counting sort by dst, then segmented sum (no float atomics)
    int eb = (E + 255) / 256;
    hist_k<<<eb, 256, 0, stream>>>(edst, histp, E);
    scan_k<<<1, 1024, 0, stream>>>(histp, startsp, curp);
    scatter_k<<<eb, 256, 0, stream>>>(esrc, edst, etyp, curp, spack, E);
    agg_acat_k<<<20000, 128, 0, stream>>>(spack, startsp, ent, rel, acat);

    // pre_emb = rrelu(A_cat @ Bcat^T)  [20000 x 128]
    gemm_nt<<<dim3(2, 313), 256, 0, stream>>>(acat, bcat, nullptr, nullptr, preb, nullptr, nullptr, nullptr,
                                              20000, 128, 384, 384, 384, 128, 0, 0, 0.f, 1);
    // aligned_all = pre_emb @ W_align^T + b_align
    gemm_nt<<<dim3(2, 313), 256, 0, stream>>>(preb, alb, bal, nullptr, alnb, nullptr, nullptr, nullptr,
                                              20000, 128, 128, 128, 128, 128, 0, 0, 0.f, 0);
    // t1 = rel_emb @ W_map1^T + b_map1  [460 x 256]
    gemm_nt<<<dim3(4, 8), 256, 0, stream>>>(relb, m1b, bm1, nullptr, t1b, nullptr, nullptr, nullptr,
                                            460, 256, 128, 128, 128, 256, 0, 0, 0.f, 0);
    // mapped_rel = t1 @ W_map2^T + b_map2  [460 x 128] (+ transposed copy, ldct=480)
    gemm_nt<<<dim3(2, 8), 256, 0, stream>>>(t1b, m2b, bm2, nullptr, mapb, mapT, nullptr, nullptr,
                                            460, 128, 256, 256, 256, 128, 480, 0, 0.f, 0);

    qrel_k<<<512, 256, 0, stream>>>(mapb, trip, qrelb, Xb);

    // attnq = q_rel @ W_attn^T + b_attn
    gemm_nt<<<dim3(2, 16), 256, 0, stream>>>(qrelb, atb, bat, nullptr, atqb, nullptr, nullptr, nullptr,
                                             1024, 128, 128, 128, 128, 128, 0, 0, 0.f, 0);
    // th1 = q_rel @ W_h1^T + b_h1
    gemm_nt<<<dim3(2, 16), 256, 0, stream>>>(qrelb, h1b, bh1, nullptr, th1b, nullptr, nullptr, nullptr,
                                             1024, 128, 128, 128, 128, 128, 0, 0, 0.f, 0);
    // predicted_hist = 0.1*(th1 @ W_h2^T + b_h2) + q_rel   (f32)
    gemm_nt<<<dim3(2, 16), 256, 0, stream>>>(th1b, h2b, bh2, predf, nullptr, nullptr, qrelb, nullptr,
                                             1024, 128, 128, 128, 128, 128, 0, 0, 0.1f, 0);
    // A = attnq @ mapped_rel^T  [1024 x 460] (f32)
    gemm_nt<<<dim3(8, 16), 256, 0, stream>>>(atqb, mapb, nullptr, amat, nullptr, nullptr, nullptr, nullptr,
                                             1024, 460, 128, 128, 128, 460, 0, 0, 0.f, 0);

    softmax_k<<<8192, 64, 0, stream>>>(amat, part, xat);

    // rel_path = attn @ mapped_rel  [8192 x 128] -> X rows 0..8191 (bf16)
    gemm_nt<<<dim3(2, 128), 256, 0, stream>>>(xat, mapT, nullptr, nullptr, Xb, nullptr, nullptr, nullptr,
                                              8192, 128, 480, 480, 480, 128, 0, 0, 0.f, 0);
    // gi = X @ w_ih^T + b_ih  [9216 x 384] (f32)
    gemm_nt<<<dim3(6, 144), 256, 0, stream>>>(Xb, wihb, b_ih, gif, nullptr, nullptr, nullptr, nullptr,
                                              9216, 384, 128, 128, 128, 384, 0, 0, 0.f, 0);
    // SubL = pre_emb[triples[:,0]] @ W_align^T + b_align  (f32)
    gemm_nt<<<dim3(2, 16), 256, 0, stream>>>(preb, alb, bal, subl, nullptr, nullptr, nullptr, trip,
                                             1024, 128, 128, 128, 128, 128, 0, 3, 0.f, 0);

    gru_k<<<64, 64, 0, stream>>>(gif, whhb, b_hh, predf, gh2f, accp + 0);

    vmul_k<<<512, 256, 0, stream>>>(subl, gh2f, Vb);

    score_k<<<dim3(313, 16), 256, 0, stream>>>(Vb, alnb, out, accp + 1, 20000);

    objdot_k<<<1024, 64, 0, stream>>>(Vb, alnb, trip, accp + 2);

    final_k<<<1, 1, 0, stream>>>(accp, out);

    (void)in_sizes; (void)n_in; (void)out_size; (void)ws_size;
}

// Round 3
// 530.482 us; speedup vs baseline: 1.4592x; 1.3220x over previous
//
#include <hip/hip_runtime.h>

typedef unsigned short u16;
typedef __attribute__((ext_vector_type(8))) short bf8v;
typedef __attribute__((ext_vector_type(4))) float f4v;

#define RRELU_SLOPE 0.22916666667f

__device__ inline float bf2f(u16 u){ unsigned int i = ((unsigned int)u) << 16; float f; __builtin_memcpy(&f, &i, 4); return f; }
__device__ inline u16 f2bf(float f){ unsigned int i; __builtin_memcpy(&i, &f, 4); unsigned int r = (i + 0x7fffu + ((i >> 16) & 1u)) >> 16; return (u16)r; }
__device__ inline float sigm(float x){ return 1.f / (1.f + expf(-x)); }
__device__ inline float fsigm(float x){ return 1.f / (1.f + __expf(-x)); }
__device__ inline float ftanh(float x){ return 2.f / (1.f + __expf(-2.f * x)) - 1.f; }

// ---------------------------------------------------------------- prep: weight casts/transposes
__global__ __launch_bounds__(256) void prep_k(
    const float* __restrict__ Wn, const float* __restrict__ Wl, const float* __restrict__ We,
    const float* __restrict__ wih, const float* __restrict__ whh,
    const float* __restrict__ m1, const float* __restrict__ m2,
    const float* __restrict__ h1, const float* __restrict__ h2,
    const float* __restrict__ attn, const float* __restrict__ alg, const float* __restrict__ rel,
    u16* __restrict__ Bcat, u16* __restrict__ wihb, u16* __restrict__ whhb,
    u16* __restrict__ m1b, u16* __restrict__ m2b, u16* __restrict__ h1b, u16* __restrict__ h2b,
    u16* __restrict__ attnb, u16* __restrict__ algb, u16* __restrict__ relb)
{
    int id = blockIdx.x * 256 + threadIdx.x;
    if (id < 49152) { // Bcat[n*384+k] : n in [0,128), k in [0,384)
        int n = id / 384, k = id % 384;
        float v = (k < 128) ? Wn[k*128 + n] : (k < 256 ? Wl[(k-128)*128 + n] : We[(k-256)*128 + n]);
        Bcat[id] = f2bf(v); return;
    }
    id -= 49152;
    if (id < 49152) { wihb[id] = f2bf(wih[id]); return; } id -= 49152;
    if (id < 49152) { whhb[id] = f2bf(whh[id]); return; } id -= 49152;
    if (id < 32768) { m1b[id]  = f2bf(m1[id]);  return; } id -= 32768;
    if (id < 32768) { m2b[id]  = f2bf(m2[id]);  return; } id -= 32768;
    if (id < 16384) { h1b[id]  = f2bf(h1[id]);  return; } id -= 16384;
    if (id < 16384) { h2b[id]  = f2bf(h2[id]);  return; } id -= 16384;
    if (id < 16384) { attnb[id]= f2bf(attn[id]);return; } id -= 16384;
    if (id < 16384) { algb[id] = f2bf(alg[id]); return; } id -= 16384;
    if (id < 58880) { relb[id] = f2bf(rel[id]); return; }
}

// ---------------------------------------------------------------- edge histogram (int atomics, 1 per edge)
__global__ __launch_bounds__(256) void hist_k(
    const int* __restrict__ dst, int* __restrict__ hist, int E)
{
    int e = blockIdx.x * 256 + threadIdx.x;
    if (e < E) atomicAdd(&hist[dst[e]], 1);
}

// ---------------------------------------------------------------- exclusive scan over 20000 bins (1 block)
__global__ __launch_bounds__(1024) void scan_k(
    const int* __restrict__ hist, int* __restrict__ starts, int* __restrict__ cursor)
{
    __shared__ int part[1024];
    int t = threadIdx.x;
    int base = t * 20;
    int s = 0;
    for (int j = 0; j < 20; ++j) { int idx = base + j; if (idx < 20000) s += hist[idx]; }
    part[t] = s;
    __syncthreads();
    for (int off = 1; off < 1024; off <<= 1) {
        int v = (t >= off) ? part[t - off] : 0;
        __syncthreads();
        part[t] += v;
        __syncthreads();
    }
    int run = (t > 0) ? part[t - 1] : 0;
    for (int j = 0; j < 20; ++j) {
        int idx = base + j;
        if (idx < 20000) { starts[idx] = run; cursor[idx] = run; run += hist[idx]; }
    }
    if (t == 1023) starts[20000] = run;
}

// ---------------------------------------------------------------- scatter edges into CSR order (packed src,typ)
__global__ __launch_bounds__(256) void scatter_k(
    const int* __restrict__ src, const int* __restrict__ dst, const int* __restrict__ typ,
    int* __restrict__ cursor, int2* __restrict__ spack, int E)
{
    int e = blockIdx.x * 256 + threadIdx.x;
    if (e >= E) return;
    int d = dst[e];
    int p = atomicAdd(&cursor[d], 1);
    spack[p] = make_int2(src[e], typ[e]);
}

// ---------------------------------------------------------------- segmented sum + fused A_cat build
__global__ __launch_bounds__(128) void agg_acat_k(
    const int2* __restrict__ spack, const int* __restrict__ starts,
    const float* __restrict__ h, const float* __restrict__ rel, u16* __restrict__ Acat)
{
    int i = blockIdx.x;           // dst entity
    int k = threadIdx.x;          // feature
    int s0 = starts[i], s1 = starts[i + 1];
    float sum = 0.f;
    for (int e = s0; e < s1; ++e) {
        int2 st = spack[e];
        sum += h[(long)st.x * 128 + k] + rel[(long)st.y * 128 + k];
    }
    bool has = s1 > s0;
    float nrm = has ? 1.f / (float)(s1 - s0) : 0.f;
    float hv = h[(long)i * 128 + k];
    long o = (long)i * 384 + k;
    Acat[o]       = f2bf(sum * nrm);
    Acat[o + 128] = has ? f2bf(hv) : (u16)0;
    Acat[o + 256] = has ? (u16)0 : f2bf(hv);
}

// ---------------------------------------------------------------- generic NT bf16 MFMA GEMM
__global__ __launch_bounds__(256) void gemm_nt(
    const u16* __restrict__ A, const u16* __restrict__ B, const float* __restrict__ bias,
    float* __restrict__ Cf, u16* __restrict__ Cbf, u16* __restrict__ CT,
    const u16* __restrict__ residb, const int* __restrict__ arows,
    int M, int N, int K, int lda, int ldb, int ldc, int ldct, int arow_stride,
    float rscale, int epi)
{
    int tid = threadIdx.x;
    int wave = tid >> 6, lane = tid & 63;
    int ln = lane & 15, q = lane >> 4;
    int bm = blockIdx.y * 64 + wave * 16;
    int bn = blockIdx.x * 64;
    int am = bm + ln; if (am >= M) am = M - 1;
    long ar = arows ? (long)arows[(long)am * arow_stride] : (long)am;
    const u16* Ap = A + ar * lda;
    int br[4];
#pragma unroll
    for (int nt = 0; nt < 4; ++nt) { int n = bn + nt*16 + ln; br[nt] = (n < N) ? n : (N - 1); }
    f4v acc[4] = {};
    for (int kc = 0; kc < K; kc += 32) {
        bf8v af = *(const bf8v*)(Ap + kc + q*8);
#pragma unroll
        for (int nt = 0; nt < 4; ++nt) {
            bf8v bv = *(const bf8v*)(B + (long)br[nt]*ldb + kc + q*8);
            acc[nt] = __builtin_amdgcn_mfma_f32_16x16x32_bf16(af, bv, acc[nt], 0, 0, 0);
        }
    }
#pragma unroll
    for (int nt = 0; nt < 4; ++nt) {
        int n = bn + nt*16 + ln;
        if (n >= N) continue;
        float bv = bias ? bias[n] : 0.f;
#pragma unroll
        for (int r = 0; r < 4; ++r) {
            int m = bm + q*4 + r;
            if (m >= M) continue;
            float v = acc[nt][r] + bv;
            if (epi == 1) v = (v >= 0.f) ? v : v * RRELU_SLOPE;
            if (residb)  v = rscale * v + bf2f(residb[(long)m*ldc + n]);
            long ci = (long)m*ldc + n;
            if (Cf)  Cf[ci]  = v;
            if (Cbf) Cbf[ci] = f2bf(v);
            if (CT)  CT[(long)n*ldct + m] = f2bf(v);
        }
    }
}

// ---------------------------------------------------------------- q_rel gather (also X tail rows)
__global__ __launch_bounds__(256) void qrel_k(
    const u16* __restrict__ mapb, const int* __restrict__ trip,
    u16* __restrict__ qrelb, u16* __restrict__ X)
{
    int id = blockIdx.x * 256 + threadIdx.x; // 1024*128
    int b = id >> 7, k = id & 127;
    int r = trip[b*3 + 1];
    u16 v = mapb[r*128 + k];
    qrelb[id] = v;
    X[(long)(8192 + b)*128 + k] = v;
}

// ---------------------------------------------------------------- masked softmax over 460, bf16 out (padded to 480)
__global__ __launch_bounds__(64) void softmax_k(
    const float* __restrict__ Amat, const float* __restrict__ part, u16* __restrict__ Xattn)
{
    int row = blockIdx.x;            // t*1024 + b
    int t = row >> 10, b = row & 1023;
    int lane = threadIdx.x;
    const float* arow = Amat + (long)b*460;
    const float* crow = part + (long)b*3680 + t*460;
    float v[8], e[8];
    float m = -1e30f;
#pragma unroll
    for (int i = 0; i < 8; ++i) {
        int r = i*64 + lane;
        e[i] = 0.f;
        if (r < 460) {
            float x = crow[r] * arow[r];
            x = (x == 0.f) ? -1e9f : x;
            v[i] = x; m = fmaxf(m, x);
        } else v[i] = -1e30f;
    }
#pragma unroll
    for (int off = 32; off; off >>= 1) m = fmaxf(m, __shfl_xor(m, off));
    float sum = 0.f;
#pragma unroll
    for (int i = 0; i < 8; ++i) {
        int r = i*64 + lane;
        if (r < 460) { e[i] = expf(v[i] - m); sum += e[i]; }
    }
#pragma unroll
    for (int off = 32; off; off >>= 1) sum += __shfl_xor(sum, off);
    float inv = 1.f / sum;
#pragma unroll
    for (int i = 0; i < 8; ++i) {
        int r = i*64 + lane;
        if (r < 460)      Xattn[(long)row*480 + r] = f2bf(e[i] * inv);
        else if (r < 480) Xattn[(long)row*480 + r] = 0;
    }
}

// ---------------------------------------------------------------- GRU scan: 256 blocks x 4 waves, 4 batch rows each
// Wave w owns gh columns [w*96, w*96+96). whh B-fragments live in registers
// across all 9 steps. gi prefetched to regs before MFMA each step.
__global__ __launch_bounds__(256) void gru_k(
    const float* __restrict__ gi, const u16* __restrict__ whhb, const float* __restrict__ bhh,
    const float* __restrict__ pred, float* __restrict__ gh2, float* __restrict__ match_acc)
{
    __shared__ u16  hbf[16][136];   // rows 4..15 stay zero; 136 pad -> 2-way-max b128 banks
    __shared__ float hf [4][128];
    __shared__ float ghl[4][388];
    __shared__ float red[4];
    int tid = threadIdx.x;
    int wave = tid >> 6, lane = tid & 63;
    int ln = lane & 15, q = lane >> 4;
    int bb = blockIdx.x * 4;
    for (int i = tid; i < 16*136; i += 256) hbf[i/136][i%136] = 0;
    for (int i = tid; i < 4*128; i += 256) hf[i>>7][i&127] = 0.f;
    // preload whh fragments: 6 N-tiles x 4 K-chunks per wave (96 VGPRs)
    bf8v bfrag[6][4];
#pragma unroll
    for (int nt = 0; nt < 6; ++nt)
#pragma unroll
        for (int kc = 0; kc < 4; ++kc)
            bfrag[nt][kc] = *(const bf8v*)(whhb + (long)(wave*96 + nt*16 + ln)*128 + kc*32 + q*8);
    int k = tid & 127;
    float br = bhh[k], bz = bhh[128 + k], bn_ = bhh[256 + k];
    __syncthreads();
    float msum = 0.f;
    for (int t = 0; t <= 8; ++t) {
        // prefetch gi (+pred) into regs; consumed after MFMA
        float gr[2], gz[2], gn[2], pv[2];
        long girow0 = (t < 8) ? ((long)t*1024 + bb) : (8192 + bb);
#pragma unroll
        for (int it = 0; it < 2; ++it) {
            int m = it*2 + (tid >> 7);
            const float* gp = gi + (girow0 + m)*384;
            gr[it] = gp[k]; gz[it] = gp[128 + k]; gn[it] = gp[256 + k];
            pv[it] = (t >= 7) ? pred[(long)(bb + m)*128 + k] : 0.f;
        }
        if (t == 8) {
#pragma unroll
            for (int it = 0; it < 2; ++it) {
                int m = it*2 + (tid >> 7);
                hf[m][k] = pv[it]; hbf[m][k] = f2bf(pv[it]);
            }
            __syncthreads();
        }
        // gh = h @ whh^T for this wave's 96 columns
        f4v acc[6] = {};
#pragma unroll
        for (int kc = 0; kc < 4; ++kc) {
            bf8v af = *(const bf8v*)&hbf[ln][kc*32 + q*8];
#pragma unroll
            for (int nt = 0; nt < 6; ++nt)
                acc[nt] = __builtin_amdgcn_mfma_f32_16x16x32_bf16(af, bfrag[nt][kc], acc[nt], 0, 0, 0);
        }
        if (q == 0) {
#pragma unroll
            for (int nt = 0; nt < 6; ++nt)
#pragma unroll
                for (int r = 0; r < 4; ++r)
                    ghl[r][wave*96 + nt*16 + ln] = acc[nt][r];
        }
        __syncthreads();
#pragma unroll
        for (int it = 0; it < 2; ++it) {
            int m = it*2 + (tid >> 7);
            float rr = fsigm(gr[it] + ghl[m][k] + br);
            float zz = fsigm(gz[it] + ghl[m][128 + k] + bz);
            float nn = ftanh(gn[it] + rr * (ghl[m][256 + k] + bn_));
            float hn = (1.f - zz) * nn + zz * hf[m][k];
            if (t == 7) { float d = pv[it] - hn; msum += d*d; }
            if (t == 8) { gh2[(long)(bb + m)*128 + k] = hn; }
            else        { hf[m][k] = hn; hbf[m][k] = f2bf(hn); }
        }
        __syncthreads();
    }
#pragma unroll
    for (int off = 32; off; off >>= 1) msum += __shfl_down(msum, off);
    if (lane == 0) red[wave] = msum;
    __syncthreads();
    if (tid == 0) atomicAdd(match_acc, red[0] + red[1] + red[2] + red[3]);
}

// ---------------------------------------------------------------- V = bf16(SubL * gh2)
__global__ __launch_bounds__(256) void vmul_k(
    const float* __restrict__ subl, const float* __restrict__ gh2, u16* __restrict__ V)
{
    int id = blockIdx.x * 256 + threadIdx.x;
    V[id] = f2bf(subl[id] * gh2[id]);
}

// ---------------------------------------------------------------- score GEMM: sigmoid store + softplus reduce
__global__ __launch_bounds__(256) void score_k(
    const u16* __restrict__ V, const u16* __restrict__ AL,
    float* __restrict__ out, float* __restrict__ sp_acc, int N)
{
    int tid = threadIdx.x;
    int wave = tid >> 6, lane = tid & 63;
    int ln = lane & 15, q = lane >> 4;
    int bm = blockIdx.y * 64 + wave * 16;
    int bn = blockIdx.x * 64;
    const u16* Ap = V + (long)(bm + ln)*128;
    int br[4];
#pragma unroll
    for (int nt = 0; nt < 4; ++nt) { int n = bn + nt*16 + ln; br[nt] = (n < N) ? n : (N - 1); }
    f4v acc[4] = {};
    for (int kc = 0; kc < 128; kc += 32) {
        bf8v af = *(const bf8v*)(Ap + kc + q*8);
#pragma unroll
        for (int nt = 0; nt < 4; ++nt) {
            bf8v bv = *(const bf8v*)(AL + (long)br[nt]*128 + kc + q*8);
            acc[nt] = __builtin_amdgcn_mfma_f32_16x16x32_bf16(af, bv, acc[nt], 0, 0, 0);
        }
    }
    float lsum = 0.f;
#pragma unroll
    for (int nt = 0; nt < 4; ++nt) {
        int n = bn + nt*16 + ln;
        if (n >= N) continue;
#pragma unroll
        for (int r = 0; r < 4; ++r) {
            int m = bm + q*4 + r;
            float s = acc[nt][r];
            out[(long)m*N + n] = 1.f / (1.f + expf(-s));
            lsum += fmaxf(s, 0.f) + log1pf(expf(-fabsf(s)));
        }
    }
#pragma unroll
    for (int off = 32; off; off >>= 1) lsum += __shfl_xor(lsum, off);
    __shared__ float red[4];
    if (lane == 0) red[wave] = lsum;
    __syncthreads();
    if (tid == 0) atomicAdd(sp_acc, red[0] + red[1] + red[2] + red[3]);
}

// ---------------------------------------------------------------- per-b score_[b, obj_b], accumulate -s
__global__ __launch_bounds__(64) void objdot_k(
    const u16* __restrict__ V, const u16* __restrict__ AL, const int* __restrict__ trip,
    float* __restrict__ obj_acc)
{
    int b = blockIdx.x, lane = threadIdx.x;
    int obj = trip[b*3 + 2];
    const u16* v = V + (long)b*128;
    const u16* a = AL + (long)obj*128;
    float s = 0.f;
    for (int k = lane; k < 128; k += 64) s += bf2f(v[k]) * bf2f(a[k]);
    for (int off = 32; off; off >>= 1) s += __shfl_down(s, off);
    if (lane == 0) atomicAdd(obj_acc, -s);
}

// ---------------------------------------------------------------- finalize scalars
__global__ void final_k(const float* __restrict__ acc, float* __restrict__ out)
{
    out[20480000] = acc[0] / (1024.f * 128.f);
    out[20480001] = (acc[1] + acc[2]) / (1024.f * 20000.f);
}

// ================================================================ host
extern "C" void kernel_launch(void* const* d_in, const int* in_sizes, int n_in,
                              void* d_out, int out_size, void* d_ws, size_t ws_size,
                              hipStream_t stream)
{
    const float* ent  = (const float*)d_in[0];
    const float* rel  = (const float*)d_in[1];
    const float* Wn   = (const float*)d_in[2];
    const float* Wl   = (const float*)d_in[3];
    const float* We   = (const float*)d_in[4];
    const float* wih  = (const float*)d_in[5];
    const float* whh  = (const float*)d_in[6];
    const float* b_ih = (const float*)d_in[7];
    const float* b_hh = (const float*)d_in[8];
    const float* Wm1  = (const float*)d_in[9];
    const float* bm1  = (const float*)d_in[10];
    const float* Wm2  = (const float*)d_in[11];
    const float* bm2  = (const float*)d_in[12];
    const float* Wh1  = (const float*)d_in[13];
    const float* bh1  = (const float*)d_in[14];
    const float* Wh2  = (const float*)d_in[15];
    const float* bh2  = (const float*)d_in[16];
    const float* Wal  = (const float*)d_in[17];
    const float* bal  = (const float*)d_in[18];
    const float* Wat  = (const float*)d_in[19];
    const float* bat  = (const float*)d_in[20];
    const float* part = (const float*)d_in[21];
    const int* esrc   = (const int*)d_in[22];
    const int* edst   = (const int*)d_in[23];
    const int* etyp   = (const int*)d_in[24];
    const int* trip   = (const int*)d_in[25];
    float* out = (float*)d_out;
    const int E = in_sizes[22];

    char* ws = (char*)d_ws;
    size_t off = 0;
    auto alloc = [&](size_t bytes) { size_t o = off; off = (off + bytes + 255) & ~(size_t)255; return o; };

    // zeroed region first (one memset)
    size_t o_acc   = alloc(256);                  // [0]=match [1]=softplus [2]=obj
    size_t o_hist  = alloc(20000 * 4);
    size_t o_mapT  = alloc(128 * 480 * 2);
    size_t zend = off;
    // non-zeroed
    size_t o_starts= alloc(20004 * 4);
    size_t o_cur   = alloc(20000 * 4);
    size_t o_spack = alloc((size_t)E * 8);
    size_t o_acat  = alloc((size_t)20000 * 384 * 2);
    size_t o_pre   = alloc((size_t)20000 * 128 * 2);
    size_t o_aln   = alloc((size_t)20000 * 128 * 2);
    size_t o_bcat  = alloc(128 * 384 * 2);
    size_t o_wih   = alloc(384 * 128 * 2);
    size_t o_whh   = alloc(384 * 128 * 2);
    size_t o_m1    = alloc(256 * 128 * 2);
    size_t o_m2    = alloc(128 * 256 * 2);
    size_t o_h1    = alloc(128 * 128 * 2);
    size_t o_h2    = alloc(128 * 128 * 2);
    size_t o_at    = alloc(128 * 128 * 2);
    size_t o_al    = alloc(128 * 128 * 2);
    size_t o_rel   = alloc(460 * 128 * 2);
    size_t o_t1    = alloc(460 * 256 * 2);
    size_t o_map   = alloc(460 * 128 * 2);
    size_t o_qrel  = alloc(1024 * 128 * 2);
    size_t o_atq   = alloc(1024 * 128 * 2);
    size_t o_th1   = alloc(1024 * 128 * 2);
    size_t o_pred  = alloc(1024 * 128 * 4);
    size_t o_amat  = alloc((size_t)1024 * 460 * 4);
    size_t o_xat   = alloc((size_t)8192 * 480 * 2);
    size_t o_X     = alloc((size_t)9216 * 128 * 2);
    size_t o_gi    = alloc((size_t)9216 * 384 * 4);
    size_t o_subl  = alloc(1024 * 128 * 4);
    size_t o_gh2   = alloc(1024 * 128 * 4);
    size_t o_V     = alloc(1024 * 128 * 2);

    float* accp  = (float*)(ws + o_acc);
    int* histp   = (int*)(ws + o_hist);
    u16* mapT    = (u16*)(ws + o_mapT);
    int* startsp = (int*)(ws + o_starts);
    int* curp    = (int*)(ws + o_cur);
    int2* spack  = (int2*)(ws + o_spack);
    u16* acat    = (u16*)(ws + o_acat);
    u16* preb    = (u16*)(ws + o_pre);
    u16* alnb    = (u16*)(ws + o_aln);
    u16* bcat    = (u16*)(ws + o_bcat);
    u16* wihb    = (u16*)(ws + o_wih);
    u16* whhb    = (u16*)(ws + o_whh);
    u16* m1b     = (u16*)(ws + o_m1);
    u16* m2b     = (u16*)(ws + o_m2);
    u16* h1b     = (u16*)(ws + o_h1);
    u16* h2b     = (u16*)(ws + o_h2);
    u16* atb     = (u16*)(ws + o_at);
    u16* alb     = (u16*)(ws + o_al);
    u16* relb    = (u16*)(ws + o_rel);
    u16* t1b     = (u16*)(ws + o_t1);
    u16* mapb    = (u16*)(ws + o_map);
    u16* qrelb   = (u16*)(ws + o_qrel);
    u16* atqb    = (u16*)(ws + o_atq);
    u16* th1b    = (u16*)(ws + o_th1);
    float* predf = (float*)(ws + o_pred);
    float* amat  = (float*)(ws + o_amat);
    u16* xat     = (u16*)(ws + o_xat);
    u16* Xb      = (u16*)(ws + o_X);
    float* gif   = (float*)(ws + o_gi);
    float* subl  = (float*)(ws + o_subl);
    float* gh2f  = (float*)(ws + o_gh2);
    u16* Vb      = (u16*)(ws + o_V);

    hipMemsetAsync(ws, 0, zend, stream);

    prep_k<<<1318, 256, 0, stream>>>(Wn, Wl, We, wih, whh, Wm1, Wm2, Wh1, Wh2, Wat, Wal, rel,
                                     bcat, wihb, whhb, m1b, m2b, h1b, h2b, atb, alb, relb);

    // counting sort by dst, then segmented sum (no float atomics)
    int eb = (E + 255) / 256;
    hist_k<<<eb, 256, 0, stream>>>(edst, histp, E);
    scan_k<<<1, 1024, 0, stream>>>(histp, startsp, curp);
    scatter_k<<<eb, 256, 0, stream>>>(esrc, edst, etyp, curp, spack, E);
    agg_acat_k<<<20000, 128, 0, stream>>>(spack, startsp, ent, rel, acat);

    // pre_emb = rrelu(A_cat @ Bcat^T)  [20000 x 128]
    gemm_nt<<<dim3(2, 313), 256, 0, stream>>>(acat, bcat, nullptr, nullptr, preb, nullptr, nullptr, nullptr,
                                              20000, 128, 384, 384, 384, 128, 0, 0, 0.f, 1);
    // aligned_all = pre_emb @ W_align^T + b_align
    gemm_nt<<<dim3(2, 313), 256, 0, stream>>>(preb, alb, bal, nullptr, alnb, nullptr, nullptr, nullptr,
                                              20000, 128, 128, 128, 128, 128, 0, 0, 0.f, 0);
    // t1 = rel_emb @ W_map1^T + b_map1  [460 x 256]
    gemm_nt<<<dim3(4, 8), 256, 0, stream>>>(relb, m1b, bm1, nullptr, t1b, nullptr, nullptr, nullptr,
                                            460, 256, 128, 128, 128, 256, 0, 0, 0.f, 0);
    // mapped_rel = t1 @ W_map2^T + b_map2  [460 x 128] (+ transposed copy, ldct=480)
    gemm_nt<<<dim3(2, 8), 256, 0, stream>>>(t1b, m2b, bm2, nullptr, mapb, mapT, nullptr, nullptr,
                                            460, 128, 256, 256, 256, 128, 480, 0, 0.f, 0);

    qrel_k<<<512, 256, 0, stream>>>(mapb, trip, qrelb, Xb);

    // attnq = q_rel @ W_attn^T + b_attn
    gemm_nt<<<dim3(2, 16), 256, 0, stream>>>(qrelb, atb, bat, nullptr, atqb, nullptr, nullptr, nullptr,
                                             1024, 128, 128, 128, 128, 128, 0, 0, 0.f, 0);
    // th1 = q_rel @ W_h1^T + b_h1
    gemm_nt<<<dim3(2, 16), 256, 0, stream>>>(qrelb, h1b, bh1, nullptr, th1b, nullptr, nullptr, nullptr,
                                             1024, 128, 128, 128, 128, 128, 0, 0, 0.f, 0);
    // predicted_hist = 0.1*(th1 @ W_h2^T + b_h2) + q_rel   (f32)
    gemm_nt<<<dim3(2, 16), 256, 0, stream>>>(th1b, h2b, bh2, predf, nullptr, nullptr, qrelb, nullptr,
                                             1024, 128, 128, 128, 128, 128, 0, 0, 0.1f, 0);
    // A = attnq @ mapped_rel^T  [1024 x 460] (f32)
    gemm_nt<<<dim3(8, 16), 256, 0, stream>>>(atqb, mapb, nullptr, amat, nullptr, nullptr, nullptr, nullptr,
                                             1024, 460, 128, 128, 128, 460, 0, 0, 0.f, 0);

    softmax_k<<<8192, 64, 0, stream>>>(amat, part, xat);

    // rel_path = attn @ mapped_rel  [8192 x 128] -> X rows 0..8191 (bf16)
    gemm_nt<<<dim3(2, 128), 256, 0, stream>>>(xat, mapT, nullptr, nullptr, Xb, nullptr, nullptr, nullptr,
                                              8192, 128, 480, 480, 480, 128, 0, 0, 0.f, 0);
    // gi = X @ w_ih^T + b_ih  [9216 x 384] (f32)
    gemm_nt<<<dim3(6, 144), 256, 0, stream>>>(Xb, wihb, b_ih, gif, nullptr, nullptr, nullptr, nullptr,
                                              9216, 384, 128, 128, 128, 384, 0, 0, 0.f, 0);
    // SubL = pre_emb[triples[:,0]] @ W_align^T + b_align  (f32)
    gemm_nt<<<dim3(2, 16), 256, 0, stream>>>(preb, alb, bal, subl, nullptr, nullptr, nullptr, trip,
                                             1024, 128, 128, 128, 128, 128, 0, 3, 0.f, 0);

    gru_k<<<256, 256, 0, stream>>>(gif, whhb, b_hh, predf, gh2f, accp + 0);

    vmul_k<<<512, 256, 0, stream>>>(subl, gh2f, Vb);

    score_k<<<dim3(313, 16), 256, 0, stream>>>(Vb, alnb, out, accp + 1, 20000);

    objdot_k<<<1024, 64, 0, stream>>>(Vb, alnb, trip, accp + 2);

    final_k<<<1, 1, 0, stream>>>(accp, out);

    (void)in_sizes; (void)n_in; (void)out_size; (void)ws_size;
}

// Round 4
// 528.021 us; speedup vs baseline: 1.4660x; 1.0047x over previous
//
#include <hip/hip_runtime.h>

typedef unsigned short u16;
typedef __attribute__((ext_vector_type(8))) short bf8v;
typedef __attribute__((ext_vector_type(4))) float f4v;

#define RRELU_SLOPE 0.22916666667f

__device__ inline float bf2f(u16 u){ unsigned int i = ((unsigned int)u) << 16; float f; __builtin_memcpy(&f, &i, 4); return f; }
__device__ inline u16 f2bf(float f){ unsigned int i; __builtin_memcpy(&i, &f, 4); unsigned int r = (i + 0x7fffu + ((i >> 16) & 1u)) >> 16; return (u16)r; }
__device__ inline float fsigm(float x){ return 1.f / (1.f + __expf(-x)); }
__device__ inline float ftanh(float x){ return 2.f / (1.f + __expf(-2.f * x)) - 1.f; }

// ---------------------------------------------------------------- prep: weight casts/transposes
__global__ __launch_bounds__(256) void prep_k(
    const float* __restrict__ Wn, const float* __restrict__ Wl, const float* __restrict__ We,
    const float* __restrict__ wih, const float* __restrict__ whh,
    const float* __restrict__ m1, const float* __restrict__ m2,
    const float* __restrict__ h1, const float* __restrict__ h2,
    const float* __restrict__ attn, const float* __restrict__ alg, const float* __restrict__ rel,
    u16* __restrict__ Bcat, u16* __restrict__ wihb, u16* __restrict__ whhb,
    u16* __restrict__ m1b, u16* __restrict__ m2b, u16* __restrict__ h1b, u16* __restrict__ h2b,
    u16* __restrict__ attnb, u16* __restrict__ algb, u16* __restrict__ relb)
{
    int id = blockIdx.x * 256 + threadIdx.x;
    if (id < 49152) { // Bcat[n*384+k] : n in [0,128), k in [0,384)
        int n = id / 384, k = id % 384;
        float v = (k < 128) ? Wn[k*128 + n] : (k < 256 ? Wl[(k-128)*128 + n] : We[(k-256)*128 + n]);
        Bcat[id] = f2bf(v); return;
    }
    id -= 49152;
    if (id < 49152) { wihb[id] = f2bf(wih[id]); return; } id -= 49152;
    if (id < 49152) { whhb[id] = f2bf(whh[id]); return; } id -= 49152;
    if (id < 32768) { m1b[id]  = f2bf(m1[id]);  return; } id -= 32768;
    if (id < 32768) { m2b[id]  = f2bf(m2[id]);  return; } id -= 32768;
    if (id < 16384) { h1b[id]  = f2bf(h1[id]);  return; } id -= 16384;
    if (id < 16384) { h2b[id]  = f2bf(h2[id]);  return; } id -= 16384;
    if (id < 16384) { attnb[id]= f2bf(attn[id]);return; } id -= 16384;
    if (id < 16384) { algb[id] = f2bf(alg[id]); return; } id -= 16384;
    if (id < 58880) { relb[id] = f2bf(rel[id]); return; }
}

// ---------------------------------------------------------------- edge histogram (int atomics, 1 per edge)
__global__ __launch_bounds__(256) void hist_k(
    const int* __restrict__ dst, int* __restrict__ hist, int E)
{
    int e = blockIdx.x * 256 + threadIdx.x;
    if (e < E) atomicAdd(&hist[dst[e]], 1);
}

// ---------------------------------------------------------------- exclusive scan over 20000 bins (1 block)
__global__ __launch_bounds__(1024) void scan_k(
    const int* __restrict__ hist, int* __restrict__ starts, int* __restrict__ cursor)
{
    __shared__ int part[1024];
    int t = threadIdx.x;
    int base = t * 20;
    int s = 0;
    for (int j = 0; j < 20; ++j) { int idx = base + j; if (idx < 20000) s += hist[idx]; }
    part[t] = s;
    __syncthreads();
    for (int off = 1; off < 1024; off <<= 1) {
        int v = (t >= off) ? part[t - off] : 0;
        __syncthreads();
        part[t] += v;
        __syncthreads();
    }
    int run = (t > 0) ? part[t - 1] : 0;
    for (int j = 0; j < 20; ++j) {
        int idx = base + j;
        if (idx < 20000) { starts[idx] = run; cursor[idx] = run; run += hist[idx]; }
    }
    if (t == 1023) starts[20000] = run;
}

// ---------------------------------------------------------------- scatter edges into CSR order (packed src,typ)
__global__ __launch_bounds__(256) void scatter_k(
    const int* __restrict__ src, const int* __restrict__ dst, const int* __restrict__ typ,
    int* __restrict__ cursor, int2* __restrict__ spack, int E)
{
    int e = blockIdx.x * 256 + threadIdx.x;
    if (e >= E) return;
    int d = dst[e];
    int p = atomicAdd(&cursor[d], 1);
    spack[p] = make_int2(src[e], typ[e]);
}

// ---------------------------------------------------------------- segmented sum + fused A_cat build
__global__ __launch_bounds__(128) void agg_acat_k(
    const int2* __restrict__ spack, const int* __restrict__ starts,
    const float* __restrict__ h, const float* __restrict__ rel, u16* __restrict__ Acat)
{
    int i = blockIdx.x;           // dst entity
    int k = threadIdx.x;          // feature
    int s0 = starts[i], s1 = starts[i + 1];
    float sum = 0.f;
    for (int e = s0; e < s1; ++e) {
        int2 st = spack[e];
        sum += h[(long)st.x * 128 + k] + rel[(long)st.y * 128 + k];
    }
    bool has = s1 > s0;
    float nrm = has ? 1.f / (float)(s1 - s0) : 0.f;
    float hv = h[(long)i * 128 + k];
    long o = (long)i * 384 + k;
    Acat[o]       = f2bf(sum * nrm);
    Acat[o + 128] = has ? f2bf(hv) : (u16)0;
    Acat[o + 256] = has ? (u16)0 : f2bf(hv);
}

// ---------------------------------------------------------------- generic NT bf16 MFMA GEMM
__global__ __launch_bounds__(256) void gemm_nt(
    const u16* __restrict__ A, const u16* __restrict__ B, const float* __restrict__ bias,
    float* __restrict__ Cf, u16* __restrict__ Cbf, u16* __restrict__ CT,
    const u16* __restrict__ residb, const int* __restrict__ arows,
    int M, int N, int K, int lda, int ldb, int ldc, int ldct, int arow_stride,
    float rscale, int epi)
{
    int tid = threadIdx.x;
    int wave = tid >> 6, lane = tid & 63;
    int ln = lane & 15, q = lane >> 4;
    int bm = blockIdx.y * 64 + wave * 16;
    int bn = blockIdx.x * 64;
    int am = bm + ln; if (am >= M) am = M - 1;
    long ar = arows ? (long)arows[(long)am * arow_stride] : (long)am;
    const u16* Ap = A + ar * lda;
    int br[4];
#pragma unroll
    for (int nt = 0; nt < 4; ++nt) { int n = bn + nt*16 + ln; br[nt] = (n < N) ? n : (N - 1); }
    f4v acc[4] = {};
    for (int kc = 0; kc < K; kc += 32) {
        bf8v af = *(const bf8v*)(Ap + kc + q*8);
#pragma unroll
        for (int nt = 0; nt < 4; ++nt) {
            bf8v bv = *(const bf8v*)(B + (long)br[nt]*ldb + kc + q*8);
            acc[nt] = __builtin_amdgcn_mfma_f32_16x16x32_bf16(af, bv, acc[nt], 0, 0, 0);
        }
    }
#pragma unroll
    for (int nt = 0; nt < 4; ++nt) {
        int n = bn + nt*16 + ln;
        if (n >= N) continue;
        float bv = bias ? bias[n] : 0.f;
#pragma unroll
        for (int r = 0; r < 4; ++r) {
            int m = bm + q*4 + r;
            if (m >= M) continue;
            float v = acc[nt][r] + bv;
            if (epi == 1) v = (v >= 0.f) ? v : v * RRELU_SLOPE;
            if (residb)  v = rscale * v + bf2f(residb[(long)m*ldc + n]);
            long ci = (long)m*ldc + n;
            if (Cf)  Cf[ci]  = v;
            if (Cbf) Cbf[ci] = f2bf(v);
            if (CT)  CT[(long)n*ldct + m] = f2bf(v);
        }
    }
}

// ---------------------------------------------------------------- q_rel gather (also X tail rows)
__global__ __launch_bounds__(256) void qrel_k(
    const u16* __restrict__ mapb, const int* __restrict__ trip,
    u16* __restrict__ qrelb, u16* __restrict__ X)
{
    int id = blockIdx.x * 256 + threadIdx.x; // 1024*128
    int b = id >> 7, k = id & 127;
    int r = trip[b*3 + 1];
    u16 v = mapb[r*128 + k];
    qrelb[id] = v;
    X[(long)(8192 + b)*128 + k] = v;
}

// ---------------------------------------------------------------- masked softmax over 460, bf16 out (padded to 480)
__global__ __launch_bounds__(64) void softmax_k(
    const float* __restrict__ Amat, const float* __restrict__ part, u16* __restrict__ Xattn)
{
    int row = blockIdx.x;            // t*1024 + b
    int t = row >> 10, b = row & 1023;
    int lane = threadIdx.x;
    const float* arow = Amat + (long)b*460;
    const float* crow = part + (long)b*3680 + t*460;
    float v[8], e[8];
    float m = -1e30f;
#pragma unroll
    for (int i = 0; i < 8; ++i) {
        int r = i*64 + lane;
        e[i] = 0.f;
        if (r < 460) {
            float x = crow[r] * arow[r];
            x = (x == 0.f) ? -1e9f : x;
            v[i] = x; m = fmaxf(m, x);
        } else v[i] = -1e30f;
    }
#pragma unroll
    for (int off = 32; off; off >>= 1) m = fmaxf(m, __shfl_xor(m, off));
    float sum = 0.f;
#pragma unroll
    for (int i = 0; i < 8; ++i) {
        int r = i*64 + lane;
        if (r < 460) { e[i] = __expf(v[i] - m); sum += e[i]; }
    }
#pragma unroll
    for (int off = 32; off; off >>= 1) sum += __shfl_xor(sum, off);
    float inv = 1.f / sum;
#pragma unroll
    for (int i = 0; i < 8; ++i) {
        int r = i*64 + lane;
        if (r < 460)      Xattn[(long)row*480 + r] = f2bf(e[i] * inv);
        else if (r < 480) Xattn[(long)row*480 + r] = 0;
    }
}

// ---------------------------------------------------------------- GRU scan: 256 blocks x 4 waves, 4 batch rows each
__global__ __launch_bounds__(256) void gru_k(
    const float* __restrict__ gi, const u16* __restrict__ whhb, const float* __restrict__ bhh,
    const float* __restrict__ pred, float* __restrict__ gh2, float* __restrict__ match_acc)
{
    __shared__ u16  hbf[16][136];   // rows 4..15 stay zero; 136 pad -> 2-way-max b128 banks
    __shared__ float hf [4][128];
    __shared__ float ghl[4][388];
    __shared__ float red[4];
    int tid = threadIdx.x;
    int wave = tid >> 6, lane = tid & 63;
    int ln = lane & 15, q = lane >> 4;
    int bb = blockIdx.x * 4;
    for (int i = tid; i < 16*136; i += 256) hbf[i/136][i%136] = 0;
    for (int i = tid; i < 4*128; i += 256) hf[i>>7][i&127] = 0.f;
    // preload whh fragments: 6 N-tiles x 4 K-chunks per wave (96 VGPRs)
    bf8v bfrag[6][4];
#pragma unroll
    for (int nt = 0; nt < 6; ++nt)
#pragma unroll
        for (int kc = 0; kc < 4; ++kc)
            bfrag[nt][kc] = *(const bf8v*)(whhb + (long)(wave*96 + nt*16 + ln)*128 + kc*32 + q*8);
    int k = tid & 127;
    float br = bhh[k], bz = bhh[128 + k], bn_ = bhh[256 + k];
    __syncthreads();
    float msum = 0.f;
    for (int t = 0; t <= 8; ++t) {
        // prefetch gi (+pred) into regs; consumed after MFMA
        float gr[2], gz[2], gn[2], pv[2];
        long girow0 = (t < 8) ? ((long)t*1024 + bb) : (8192 + bb);
#pragma unroll
        for (int it = 0; it < 2; ++it) {
            int m = it*2 + (tid >> 7);
            const float* gp = gi + (girow0 + m)*384;
            gr[it] = gp[k]; gz[it] = gp[128 + k]; gn[it] = gp[256 + k];
            pv[it] = (t >= 7) ? pred[(long)(bb + m)*128 + k] : 0.f;
        }
        if (t == 8) {
#pragma unroll
            for (int it = 0; it < 2; ++it) {
                int m = it*2 + (tid >> 7);
                hf[m][k] = pv[it]; hbf[m][k] = f2bf(pv[it]);
            }
            __syncthreads();
        }
        // gh = h @ whh^T for this wave's 96 columns
        f4v acc[6] = {};
#pragma unroll
        for (int kc = 0; kc < 4; ++kc) {
            bf8v af = *(const bf8v*)&hbf[ln][kc*32 + q*8];
#pragma unroll
            for (int nt = 0; nt < 6; ++nt)
                acc[nt] = __builtin_amdgcn_mfma_f32_16x16x32_bf16(af, bfrag[nt][kc], acc[nt], 0, 0, 0);
        }
        if (q == 0) {
#pragma unroll
            for (int nt = 0; nt < 6; ++nt)
#pragma unroll
                for (int r = 0; r < 4; ++r)
                    ghl[r][wave*96 + nt*16 + ln] = acc[nt][r];
        }
        __syncthreads();
#pragma unroll
        for (int it = 0; it < 2; ++it) {
            int m = it*2 + (tid >> 7);
            float rr = fsigm(gr[it] + ghl[m][k] + br);
            float zz = fsigm(gz[it] + ghl[m][128 + k] + bz);
            float nn = ftanh(gn[it] + rr * (ghl[m][256 + k] + bn_));
            float hn = (1.f - zz) * nn + zz * hf[m][k];
            if (t == 7) { float d = pv[it] - hn; msum += d*d; }
            if (t == 8) { gh2[(long)(bb + m)*128 + k] = hn; }
            else        { hf[m][k] = hn; hbf[m][k] = f2bf(hn); }
        }
        __syncthreads();
    }
#pragma unroll
    for (int off = 32; off; off >>= 1) msum += __shfl_down(msum, off);
    if (lane == 0) red[wave] = msum;
    __syncthreads();
    if (tid == 0) atomicAdd(match_acc, red[0] + red[1] + red[2] + red[3]);
}

// ---------------------------------------------------------------- V = bf16(SubL * gh2)
__global__ __launch_bounds__(256) void vmul_k(
    const float* __restrict__ subl, const float* __restrict__ gh2, u16* __restrict__ V)
{
    int id = blockIdx.x * 256 + threadIdx.x;
    V[id] = f2bf(subl[id] * gh2[id]);
}

// ---------------------------------------------------------------- score GEMM: fast sigmoid store + softplus reduce
// e = exp(-|s|), d = 1+e:  sigma = (s>=0 ? 1 : e)/d ;  softplus(s) = max(s,0) + log(d)
__global__ __launch_bounds__(256) void score_k(
    const u16* __restrict__ V, const u16* __restrict__ AL,
    float* __restrict__ out, float* __restrict__ sp_acc, int N)
{
    int tid = threadIdx.x;
    int wave = tid >> 6, lane = tid & 63;
    int ln = lane & 15, q = lane >> 4;
    int bm = blockIdx.y * 64 + wave * 16;
    int bn = blockIdx.x * 64;
    const u16* Ap = V + (long)(bm + ln)*128;
    int br[4];
#pragma unroll
    for (int nt = 0; nt < 4; ++nt) { int n = bn + nt*16 + ln; br[nt] = (n < N) ? n : (N - 1); }
    f4v acc[4] = {};
    for (int kc = 0; kc < 128; kc += 32) {
        bf8v af = *(const bf8v*)(Ap + kc + q*8);
#pragma unroll
        for (int nt = 0; nt < 4; ++nt) {
            bf8v bv = *(const bf8v*)(AL + (long)br[nt]*128 + kc + q*8);
            acc[nt] = __builtin_amdgcn_mfma_f32_16x16x32_bf16(af, bv, acc[nt], 0, 0, 0);
        }
    }
    float lsum = 0.f;
#pragma unroll
    for (int nt = 0; nt < 4; ++nt) {
        int n = bn + nt*16 + ln;
        if (n >= N) continue;
#pragma unroll
        for (int r = 0; r < 4; ++r) {
            int m = bm + q*4 + r;
            float s = acc[nt][r];
            float e = __expf(-fabsf(s));
            float inv = 1.f / (1.f + e);
            out[(long)m*N + n] = (s >= 0.f) ? inv : e * inv;
            lsum += fmaxf(s, 0.f) + __logf(1.f + e);
        }
    }
#pragma unroll
    for (int off = 32; off; off >>= 1) lsum += __shfl_xor(lsum, off);
    __shared__ float red[4];
    if (lane == 0) red[wave] = lsum;
    __syncthreads();
    if (tid == 0) atomicAdd(sp_acc, red[0] + red[1] + red[2] + red[3]);
}

// ---------------------------------------------------------------- per-b score_[b, obj_b], accumulate -s
__global__ __launch_bounds__(64) void objdot_k(
    const u16* __restrict__ V, const u16* __restrict__ AL, const int* __restrict__ trip,
    float* __restrict__ obj_acc)
{
    int b = blockIdx.x, lane = threadIdx.x;
    int obj = trip[b*3 + 2];
    const u16* v = V + (long)b*128;
    const u16* a = AL + (long)obj*128;
    float s = 0.f;
    for (int k = lane; k < 128; k += 64) s += bf2f(v[k]) * bf2f(a[k]);
    for (int off = 32; off; off >>= 1) s += __shfl_down(s, off);
    if (lane == 0) atomicAdd(obj_acc, -s);
}

// ---------------------------------------------------------------- finalize scalars
__global__ void final_k(const float* __restrict__ acc, float* __restrict__ out)
{
    out[20480000] = acc[0] / (1024.f * 128.f);
    out[20480001] = (acc[1] + acc[2]) / (1024.f * 20000.f);
}

// ================================================================ host
extern "C" void kernel_launch(void* const* d_in, const int* in_sizes, int n_in,
                              void* d_out, int out_size, void* d_ws, size_t ws_size,
                              hipStream_t stream)
{
    const float* ent  = (const float*)d_in[0];
    const float* rel  = (const float*)d_in[1];
    const float* Wn   = (const float*)d_in[2];
    const float* Wl   = (const float*)d_in[3];
    const float* We   = (const float*)d_in[4];
    const float* wih  = (const float*)d_in[5];
    const float* whh  = (const float*)d_in[6];
    const float* b_ih = (const float*)d_in[7];
    const float* b_hh = (const float*)d_in[8];
    const float* Wm1  = (const float*)d_in[9];
    const float* bm1  = (const float*)d_in[10];
    const float* Wm2  = (const float*)d_in[11];
    const float* bm2  = (const float*)d_in[12];
    const float* Wh1  = (const float*)d_in[13];
    const float* bh1  = (const float*)d_in[14];
    const float* Wh2  = (const float*)d_in[15];
    const float* bh2  = (const float*)d_in[16];
    const float* Wal  = (const float*)d_in[17];
    const float* bal  = (const float*)d_in[18];
    const float* Wat  = (const float*)d_in[19];
    const float* bat  = (const float*)d_in[20];
    const float* part = (const float*)d_in[21];
    const int* esrc   = (const int*)d_in[22];
    const int* edst   = (const int*)d_in[23];
    const int* etyp   = (const int*)d_in[24];
    const int* trip   = (const int*)d_in[25];
    float* out = (float*)d_out;
    const int E = in_sizes[22];

    char* ws = (char*)d_ws;
    size_t off = 0;
    auto alloc = [&](size_t bytes) { size_t o = off; off = (off + bytes + 255) & ~(size_t)255; return o; };

    // zeroed region first (one memset)
    size_t o_acc   = alloc(256);                  // [0]=match [1]=softplus [2]=obj
    size_t o_hist  = alloc(20000 * 4);
    size_t o_mapT  = alloc(128 * 480 * 2);
    size_t zend = off;
    // non-zeroed
    size_t o_starts= alloc(20004 * 4);
    size_t o_cur   = alloc(20000 * 4);
    size_t o_spack = alloc((size_t)E * 8);
    size_t o_acat  = alloc((size_t)20000 * 384 * 2);
    size_t o_pre   = alloc((size_t)20000 * 128 * 2);
    size_t o_aln   = alloc((size_t)20000 * 128 * 2);
    size_t o_bcat  = alloc(128 * 384 * 2);
    size_t o_wih   = alloc(384 * 128 * 2);
    size_t o_whh   = alloc(384 * 128 * 2);
    size_t o_m1    = alloc(256 * 128 * 2);
    size_t o_m2    = alloc(128 * 256 * 2);
    size_t o_h1    = alloc(128 * 128 * 2);
    size_t o_h2    = alloc(128 * 128 * 2);
    size_t o_at    = alloc(128 * 128 * 2);
    size_t o_al    = alloc(128 * 128 * 2);
    size_t o_rel   = alloc(460 * 128 * 2);
    size_t o_t1    = alloc(460 * 256 * 2);
    size_t o_map   = alloc(460 * 128 * 2);
    size_t o_qrel  = alloc(1024 * 128 * 2);
    size_t o_atq   = alloc(1024 * 128 * 2);
    size_t o_th1   = alloc(1024 * 128 * 2);
    size_t o_pred  = alloc(1024 * 128 * 4);
    size_t o_amat  = alloc((size_t)1024 * 460 * 4);
    size_t o_xat   = alloc((size_t)8192 * 480 * 2);
    size_t o_X     = alloc((size_t)9216 * 128 * 2);
    size_t o_gi    = alloc((size_t)9216 * 384 * 4);
    size_t o_subl  = alloc(1024 * 128 * 4);
    size_t o_gh2   = alloc(1024 * 128 * 4);
    size_t o_V     = alloc(1024 * 128 * 2);

    float* accp  = (float*)(ws + o_acc);
    int* histp   = (int*)(ws + o_hist);
    u16* mapT    = (u16*)(ws + o_mapT);
    int* startsp = (int*)(ws + o_starts);
    int* curp    = (int*)(ws + o_cur);
    int2* spack  = (int2*)(ws + o_spack);
    u16* acat    = (u16*)(ws + o_acat);
    u16* preb    = (u16*)(ws + o_pre);
    u16* alnb    = (u16*)(ws + o_aln);
    u16* bcat    = (u16*)(ws + o_bcat);
    u16* wihb    = (u16*)(ws + o_wih);
    u16* whhb    = (u16*)(ws + o_whh);
    u16* m1b     = (u16*)(ws + o_m1);
    u16* m2b     = (u16*)(ws + o_m2);
    u16* h1b     = (u16*)(ws + o_h1);
    u16* h2b     = (u16*)(ws + o_h2);
    u16* atb     = (u16*)(ws + o_at);
    u16* alb     = (u16*)(ws + o_al);
    u16* relb    = (u16*)(ws + o_rel);
    u16* t1b     = (u16*)(ws + o_t1);
    u16* mapb    = (u16*)(ws + o_map);
    u16* qrelb   = (u16*)(ws + o_qrel);
    u16* atqb    = (u16*)(ws + o_atq);
    u16* th1b    = (u16*)(ws + o_th1);
    float* predf = (float*)(ws + o_pred);
    float* amat  = (float*)(ws + o_amat);
    u16* xat     = (u16*)(ws + o_xat);
    u16* Xb      = (u16*)(ws + o_X);
    float* gif   = (float*)(ws + o_gi);
    float* subl  = (float*)(ws + o_subl);
    float* gh2f  = (float*)(ws + o_gh2);
    u16* Vb      = (u16*)(ws + o_V);

    hipMemsetAsync(ws, 0, zend, stream);

    prep_k<<<1318, 256, 0, stream>>>(Wn, Wl, We, wih, whh, Wm1, Wm2, Wh1, Wh2, Wat, Wal, rel,
                                     bcat, wihb, whhb, m1b, m2b, h1b, h2b, atb, alb, relb);

    // counting sort by dst, then segmented sum (no float atomics)
    int eb = (E + 255) / 256;
    hist_k<<<eb, 256, 0, stream>>>(edst, histp, E);
    scan_k<<<1, 1024, 0, stream>>>(histp, startsp, curp);
    scatter_k<<<eb, 256, 0, stream>>>(esrc, edst, etyp, curp, spack, E);
    agg_acat_k<<<20000, 128, 0, stream>>>(spack, startsp, ent, rel, acat);

    // pre_emb = rrelu(A_cat @ Bcat^T)  [20000 x 128]
    gemm_nt<<<dim3(2, 313), 256, 0, stream>>>(acat, bcat, nullptr, nullptr, preb, nullptr, nullptr, nullptr,
                                              20000, 128, 384, 384, 384, 128, 0, 0, 0.f, 1);
    // aligned_all = pre_emb @ W_align^T + b_align
    gemm_nt<<<dim3(2, 313), 256, 0, stream>>>(preb, alb, bal, nullptr, alnb, nullptr, nullptr, nullptr,
                                              20000, 128, 128, 128, 128, 128, 0, 0, 0.f, 0);
    // t1 = rel_emb @ W_map1^T + b_map1  [460 x 256]
    gemm_nt<<<dim3(4, 8), 256, 0, stream>>>(relb, m1b, bm1, nullptr, t1b, nullptr, nullptr, nullptr,
                                            460, 256, 128, 128, 128, 256, 0, 0, 0.f, 0);
    // mapped_rel = t1 @ W_map2^T + b_map2  [460 x 128] (+ transposed copy, ldct=480)
    gemm_nt<<<dim3(2, 8), 256, 0, stream>>>(t1b, m2b, bm2, nullptr, mapb, mapT, nullptr, nullptr,
                                            460, 128, 256, 256, 256, 128, 480, 0, 0.f, 0);

    qrel_k<<<512, 256, 0, stream>>>(mapb, trip, qrelb, Xb);

    // attnq = q_rel @ W_attn^T + b_attn
    gemm_nt<<<dim3(2, 16), 256, 0, stream>>>(qrelb, atb, bat, nullptr, atqb, nullptr, nullptr, nullptr,
                                             1024, 128, 128, 128, 128, 128, 0, 0, 0.f, 0);
    // th1 = q_rel @ W_h1^T + b_h1
    gemm_nt<<<dim3(2, 16), 256, 0, stream>>>(qrelb, h1b, bh1, nullptr, th1b, nullptr, nullptr, nullptr,
                                             1024, 128, 128, 128, 128, 128, 0, 0, 0.f, 0);
    // predicted_hist = 0.1*(th1 @ W_h2^T + b_h2) + q_rel   (f32)
    gemm_nt<<<dim3(2, 16), 256, 0, stream>>>(th1b, h2b, bh2, predf, nullptr, nullptr, qrelb, nullptr,
                                             1024, 128, 128, 128, 128, 128, 0, 0, 0.1f, 0);
    // A = attnq @ mapped_rel^T  [1024 x 460] (f32)
    gemm_nt<<<dim3(8, 16), 256, 0, stream>>>(atqb, mapb, nullptr, amat, nullptr, nullptr, nullptr, nullptr,
                                             1024, 460, 128, 128, 128, 460, 0, 0, 0.f, 0);

    softmax_k<<<8192, 64, 0, stream>>>(amat, part, xat);

    // rel_path = attn @ mapped_rel  [8192 x 128] -> X rows 0..8191 (bf16)
    gemm_nt<<<dim3(2, 128), 256, 0, stream>>>(xat, mapT, nullptr, nullptr, Xb, nullptr, nullptr, nullptr,
                                              8192, 128, 480, 480, 480, 128, 0, 0, 0.f, 0);
    // gi = X @ w_ih^T + b_ih  [9216 x 384] (f32)
    gemm_nt<<<dim3(6, 144), 256, 0, stream>>>(Xb, wihb, b_ih, gif, nullptr, nullptr, nullptr, nullptr,
                                              9216, 384, 128, 128, 128, 384, 0, 0, 0.f, 0);
    // SubL = pre_emb[triples[:,0]] @ W_align^T + b_align  (f32)
    gemm_nt<<<dim3(2, 16), 256, 0, stream>>>(preb, alb, bal, subl, nullptr, nullptr, nullptr, trip,
                                             1024, 128, 128, 128, 128, 128, 0, 3, 0.f, 0);

    gru_k<<<256, 256, 0, stream>>>(gif, whhb, b_hh, predf, gh2f, accp + 0);

    vmul_k<<<512, 256, 0, stream>>>(subl, gh2f, Vb);

    score_k<<<dim3(313, 16), 256, 0, stream>>>(Vb, alnb, out, accp + 1, 20000);

    objdot_k<<<1024, 64, 0, stream>>>(Vb, alnb, trip, accp + 2);

    final_k<<<1, 1, 0, stream>>>(accp, out);

    (void)in_sizes; (void)n_in; (void)out_size; (void)ws_size;
}

// Round 5
// 476.333 us; speedup vs baseline: 1.6250x; 1.1085x over previous
//
#include <hip/hip_runtime.h>

typedef unsigned short u16;
typedef unsigned int u32;
typedef __attribute__((ext_vector_type(8))) short bf8v;
typedef __attribute__((ext_vector_type(4))) float f4v;

#define RRELU_SLOPE 0.22916666667f

__device__ inline float bf2f(u16 u){ unsigned int i = ((unsigned int)u) << 16; float f; __builtin_memcpy(&f, &i, 4); return f; }
__device__ inline u16 f2bf(float f){ unsigned int i; __builtin_memcpy(&i, &f, 4); unsigned int r = (i + 0x7fffu + ((i >> 16) & 1u)) >> 16; return (u16)r; }
__device__ inline float fsigm(float x){ return 1.f / (1.f + __expf(-x)); }
__device__ inline float ftanh(float x){ return 2.f / (1.f + __expf(-2.f * x)) - 1.f; }

// ---------------------------------------------------------------- prep: weight casts/transposes
__global__ __launch_bounds__(256) void prep_k(
    const float* __restrict__ Wn, const float* __restrict__ Wl, const float* __restrict__ We,
    const float* __restrict__ wih, const float* __restrict__ whh,
    const float* __restrict__ m1, const float* __restrict__ m2,
    const float* __restrict__ h1, const float* __restrict__ h2,
    const float* __restrict__ attn, const float* __restrict__ alg, const float* __restrict__ rel,
    u16* __restrict__ Bcat, u16* __restrict__ wihb, u16* __restrict__ whhb,
    u16* __restrict__ m1b, u16* __restrict__ m2b, u16* __restrict__ h1b, u16* __restrict__ h2b,
    u16* __restrict__ attnb, u16* __restrict__ algb, u16* __restrict__ relb)
{
    int id = blockIdx.x * 256 + threadIdx.x;
    if (id < 49152) { // Bcat[n*384+k] : n in [0,128), k in [0,384)
        int n = id / 384, k = id % 384;
        float v = (k < 128) ? Wn[k*128 + n] : (k < 256 ? Wl[(k-128)*128 + n] : We[(k-256)*128 + n]);
        Bcat[id] = f2bf(v); return;
    }
    id -= 49152;
    if (id < 49152) { wihb[id] = f2bf(wih[id]); return; } id -= 49152;
    if (id < 49152) { whhb[id] = f2bf(whh[id]); return; } id -= 49152;
    if (id < 32768) { m1b[id]  = f2bf(m1[id]);  return; } id -= 32768;
    if (id < 32768) { m2b[id]  = f2bf(m2[id]);  return; } id -= 32768;
    if (id < 16384) { h1b[id]  = f2bf(h1[id]);  return; } id -= 16384;
    if (id < 16384) { h2b[id]  = f2bf(h2[id]);  return; } id -= 16384;
    if (id < 16384) { attnb[id]= f2bf(attn[id]);return; } id -= 16384;
    if (id < 16384) { algb[id] = f2bf(alg[id]); return; } id -= 16384;
    if (id < 58880) { relb[id] = f2bf(rel[id]); return; }
}

// ---------------------------------------------------------------- ent_emb -> bf16 cast
__global__ __launch_bounds__(256) void entcast_k(
    const float* __restrict__ ent, u16* __restrict__ entb)
{
    int id = blockIdx.x * 256 + threadIdx.x; // 20000*128
    entb[id] = f2bf(ent[id]);
}

// ---------------------------------------------------------------- edge histogram (int atomics, 1 per edge)
__global__ __launch_bounds__(256) void hist_k(
    const int* __restrict__ dst, int* __restrict__ hist, int E)
{
    int e = blockIdx.x * 256 + threadIdx.x;
    if (e < E) atomicAdd(&hist[dst[e]], 1);
}

// ---------------------------------------------------------------- exclusive scan over 20000 bins (1 block)
__global__ __launch_bounds__(1024) void scan_k(
    const int* __restrict__ hist, int* __restrict__ starts, int* __restrict__ cursor)
{
    __shared__ int part[1024];
    int t = threadIdx.x;
    int base = t * 20;
    int s = 0;
    for (int j = 0; j < 20; ++j) { int idx = base + j; if (idx < 20000) s += hist[idx]; }
    part[t] = s;
    __syncthreads();
    for (int off = 1; off < 1024; off <<= 1) {
        int v = (t >= off) ? part[t - off] : 0;
        __syncthreads();
        part[t] += v;
        __syncthreads();
    }
    int run = (t > 0) ? part[t - 1] : 0;
    for (int j = 0; j < 20; ++j) {
        int idx = base + j;
        if (idx < 20000) { starts[idx] = run; cursor[idx] = run; run += hist[idx]; }
    }
    if (t == 1023) starts[20000] = run;
}

// ---------------------------------------------------------------- scatter edges into CSR order (packed src,typ)
__global__ __launch_bounds__(256) void scatter_k(
    const int* __restrict__ src, const int* __restrict__ dst, const int* __restrict__ typ,
    int* __restrict__ cursor, int2* __restrict__ spack, int E)
{
    int e = blockIdx.x * 256 + threadIdx.x;
    if (e >= E) return;
    int d = dst[e];
    int p = atomicAdd(&cursor[d], 1);
    spack[p] = make_int2(src[e], typ[e]);
}

// ---------------------------------------------------------------- segmented sum + fused A_cat build (bf16 gathers, u32-packed)
__global__ __launch_bounds__(64) void agg_acat_k(
    const int2* __restrict__ spack, const int* __restrict__ starts,
    const u32* __restrict__ hb, const u32* __restrict__ rb, u32* __restrict__ Acat32)
{
    int i = blockIdx.x;            // dst entity
    int lane = threadIdx.x;        // 0..63, covers features 2*lane, 2*lane+1
    int s0 = starts[i], s1 = starts[i + 1];
    float sx = 0.f, sy = 0.f;
    for (int e = s0; e < s1; ++e) {
        int2 st = spack[e];
        u32 a = hb[(long)st.x * 64 + lane];
        u32 r = rb[(long)st.y * 64 + lane];
        sx += bf2f((u16)(a & 0xffff)) + bf2f((u16)(r & 0xffff));
        sy += bf2f((u16)(a >> 16))    + bf2f((u16)(r >> 16));
    }
    bool has = s1 > s0;
    float nrm = has ? 1.f / (float)(s1 - s0) : 0.f;
    u32 hv = hb[(long)i * 64 + lane];
    u32 agg = (u32)f2bf(sx * nrm) | ((u32)f2bf(sy * nrm) << 16);
    long o = (long)i * 192 + lane;
    Acat32[o]       = agg;
    Acat32[o + 64]  = has ? hv : 0u;
    Acat32[o + 128] = has ? 0u : hv;
}

// ---------------------------------------------------------------- generic NT bf16 MFMA GEMM
__global__ __launch_bounds__(256) void gemm_nt(
    const u16* __restrict__ A, const u16* __restrict__ B, const float* __restrict__ bias,
    float* __restrict__ Cf, u16* __restrict__ Cbf, u16* __restrict__ CT,
    const u16* __restrict__ residb, const int* __restrict__ arows,
    int M, int N, int K, int lda, int ldb, int ldc, int ldct, int arow_stride,
    float rscale, int epi)
{
    int tid = threadIdx.x;
    int wave = tid >> 6, lane = tid & 63;
    int ln = lane & 15, q = lane >> 4;
    int bm = blockIdx.y * 64 + wave * 16;
    int bn = blockIdx.x * 64;
    int am = bm + ln; if (am >= M) am = M - 1;
    long ar = arows ? (long)arows[(long)am * arow_stride] : (long)am;
    const u16* Ap = A + ar * lda;
    int br[4];
#pragma unroll
    for (int nt = 0; nt < 4; ++nt) { int n = bn + nt*16 + ln; br[nt] = (n < N) ? n : (N - 1); }
    f4v acc[4] = {};
    for (int kc = 0; kc < K; kc += 32) {
        bf8v af = *(const bf8v*)(Ap + kc + q*8);
#pragma unroll
        for (int nt = 0; nt < 4; ++nt) {
            bf8v bv = *(const bf8v*)(B + (long)br[nt]*ldb + kc + q*8);
            acc[nt] = __builtin_amdgcn_mfma_f32_16x16x32_bf16(af, bv, acc[nt], 0, 0, 0);
        }
    }
#pragma unroll
    for (int nt = 0; nt < 4; ++nt) {
        int n = bn + nt*16 + ln;
        if (n >= N) continue;
        float bv = bias ? bias[n] : 0.f;
#pragma unroll
        for (int r = 0; r < 4; ++r) {
            int m = bm + q*4 + r;
            if (m >= M) continue;
            float v = acc[nt][r] + bv;
            if (epi == 1) v = (v >= 0.f) ? v : v * RRELU_SLOPE;
            if (residb)  v = rscale * v + bf2f(residb[(long)m*ldc + n]);
            long ci = (long)m*ldc + n;
            if (Cf)  Cf[ci]  = v;
            if (Cbf) Cbf[ci] = f2bf(v);
            if (CT)  CT[(long)n*ldct + m] = f2bf(v);
        }
    }
}

// ---------------------------------------------------------------- q_rel gather (also X tail rows)
__global__ __launch_bounds__(256) void qrel_k(
    const u16* __restrict__ mapb, const int* __restrict__ trip,
    u16* __restrict__ qrelb, u16* __restrict__ X)
{
    int id = blockIdx.x * 256 + threadIdx.x; // 1024*128
    int b = id >> 7, k = id & 127;
    int r = trip[b*3 + 1];
    u16 v = mapb[r*128 + k];
    qrelb[id] = v;
    X[(long)(8192 + b)*128 + k] = v;
}

// ---------------------------------------------------------------- masked softmax over 460, bf16 out (padded to 480)
__global__ __launch_bounds__(64) void softmax_k(
    const float* __restrict__ Amat, const float* __restrict__ part, u16* __restrict__ Xattn)
{
    int row = blockIdx.x;            // t*1024 + b
    int t = row >> 10, b = row & 1023;
    int lane = threadIdx.x;
    const float* arow = Amat + (long)b*460;
    const float* crow = part + (long)b*3680 + t*460;
    float v[8], e[8];
    float m = -1e30f;
#pragma unroll
    for (int i = 0; i < 8; ++i) {
        int r = i*64 + lane;
        e[i] = 0.f;
        if (r < 460) {
            float x = crow[r] * arow[r];
            x = (x == 0.f) ? -1e9f : x;
            v[i] = x; m = fmaxf(m, x);
        } else v[i] = -1e30f;
    }
#pragma unroll
    for (int off = 32; off; off >>= 1) m = fmaxf(m, __shfl_xor(m, off));
    float sum = 0.f;
#pragma unroll
    for (int i = 0; i < 8; ++i) {
        int r = i*64 + lane;
        if (r < 460) { e[i] = __expf(v[i] - m); sum += e[i]; }
    }
#pragma unroll
    for (int off = 32; off; off >>= 1) sum += __shfl_xor(sum, off);
    float inv = 1.f / sum;
#pragma unroll
    for (int i = 0; i < 8; ++i) {
        int r = i*64 + lane;
        if (r < 460)      Xattn[(long)row*480 + r] = f2bf(e[i] * inv);
        else if (r < 480) Xattn[(long)row*480 + r] = 0;
    }
}

// ---------------------------------------------------------------- GRU scan: 256 blocks x 4 waves, 4 batch rows each
__global__ __launch_bounds__(256) void gru_k(
    const float* __restrict__ gi, const u16* __restrict__ whhb, const float* __restrict__ bhh,
    const float* __restrict__ pred, float* __restrict__ gh2, float* __restrict__ match_acc)
{
    __shared__ u16  hbf[16][136];   // rows 4..15 stay zero; 136 pad -> 2-way-max b128 banks
    __shared__ float hf [4][128];
    __shared__ float ghl[4][388];
    __shared__ float red[4];
    int tid = threadIdx.x;
    int wave = tid >> 6, lane = tid & 63;
    int ln = lane & 15, q = lane >> 4;
    int bb = blockIdx.x * 4;
    for (int i = tid; i < 16*136; i += 256) hbf[i/136][i%136] = 0;
    for (int i = tid; i < 4*128; i += 256) hf[i>>7][i&127] = 0.f;
    // preload whh fragments: 6 N-tiles x 4 K-chunks per wave (96 VGPRs)
    bf8v bfrag[6][4];
#pragma unroll
    for (int nt = 0; nt < 6; ++nt)
#pragma unroll
        for (int kc = 0; kc < 4; ++kc)
            bfrag[nt][kc] = *(const bf8v*)(whhb + (long)(wave*96 + nt*16 + ln)*128 + kc*32 + q*8);
    int k = tid & 127;
    float br = bhh[k], bz = bhh[128 + k], bn_ = bhh[256 + k];
    __syncthreads();
    float msum = 0.f;
    for (int t = 0; t <= 8; ++t) {
        // prefetch gi (+pred) into regs; consumed after MFMA
        float gr[2], gz[2], gn[2], pv[2];
        long girow0 = (t < 8) ? ((long)t*1024 + bb) : (8192 + bb);
#pragma unroll
        for (int it = 0; it < 2; ++it) {
            int m = it*2 + (tid >> 7);
            const float* gp = gi + (girow0 + m)*384;
            gr[it] = gp[k]; gz[it] = gp[128 + k]; gn[it] = gp[256 + k];
            pv[it] = (t >= 7) ? pred[(long)(bb + m)*128 + k] : 0.f;
        }
        if (t == 8) {
#pragma unroll
            for (int it = 0; it < 2; ++it) {
                int m = it*2 + (tid >> 7);
                hf[m][k] = pv[it]; hbf[m][k] = f2bf(pv[it]);
            }
            __syncthreads();
        }
        // gh = h @ whh^T for this wave's 96 columns
        f4v acc[6] = {};
#pragma unroll
        for (int kc = 0; kc < 4; ++kc) {
            bf8v af = *(const bf8v*)&hbf[ln][kc*32 + q*8];
#pragma unroll
            for (int nt = 0; nt < 6; ++nt)
                acc[nt] = __builtin_amdgcn_mfma_f32_16x16x32_bf16(af, bfrag[nt][kc], acc[nt], 0, 0, 0);
        }
        if (q == 0) {
#pragma unroll
            for (int nt = 0; nt < 6; ++nt)
#pragma unroll
                for (int r = 0; r < 4; ++r)
                    ghl[r][wave*96 + nt*16 + ln] = acc[nt][r];
        }
        __syncthreads();
#pragma unroll
        for (int it = 0; it < 2; ++it) {
            int m = it*2 + (tid >> 7);
            float rr = fsigm(gr[it] + ghl[m][k] + br);
            float zz = fsigm(gz[it] + ghl[m][128 + k] + bz);
            float nn = ftanh(gn[it] + rr * (ghl[m][256 + k] + bn_));
            float hn = (1.f - zz) * nn + zz * hf[m][k];
            if (t == 7) { float d = pv[it] - hn; msum += d*d; }
            if (t == 8) { gh2[(long)(bb + m)*128 + k] = hn; }
            else        { hf[m][k] = hn; hbf[m][k] = f2bf(hn); }
        }
        __syncthreads();
    }
#pragma unroll
    for (int off = 32; off; off >>= 1) msum += __shfl_down(msum, off);
    if (lane == 0) red[wave] = msum;
    __syncthreads();
    if (tid == 0) atomicAdd(match_acc, red[0] + red[1] + red[2] + red[3]);
}

// ---------------------------------------------------------------- V = bf16(SubL * gh2)
__global__ __launch_bounds__(256) void vmul_k(
    const float* __restrict__ subl, const float* __restrict__ gh2, u16* __restrict__ V)
{
    int id = blockIdx.x * 256 + threadIdx.x;
    V[id] = f2bf(subl[id] * gh2[id]);
}

// ---------------------------------------------------------------- score GEMM: 64x64/wave, NT stores, softplus reduce
// e = exp(-|s|), d = 1+e:  sigma = (s>=0 ? 1 : e)/d ;  softplus(s) = max(s,0) + log(d)
__global__ __launch_bounds__(256) void score_k(
    const u16* __restrict__ V, const u16* __restrict__ AL,
    float* __restrict__ out, float* __restrict__ sp_acc, int N)
{
    int tid = threadIdx.x;
    int wave = tid >> 6, lane = tid & 63;
    int ln = lane & 15, q = lane >> 4;
    int bm = blockIdx.y * 128 + (wave >> 1) * 64;
    int bn = blockIdx.x * 128 + (wave & 1) * 64;
    int br[4];
#pragma unroll
    for (int nt = 0; nt < 4; ++nt) { int n = bn + nt*16 + ln; br[nt] = (n < N) ? n : (N - 1); }
    f4v acc[4][4] = {};
    for (int kc = 0; kc < 128; kc += 32) {
        bf8v a[4], b[4];
#pragma unroll
        for (int mt = 0; mt < 4; ++mt)
            a[mt] = *(const bf8v*)(V + (long)(bm + mt*16 + ln)*128 + kc + q*8);
#pragma unroll
        for (int nt = 0; nt < 4; ++nt)
            b[nt] = *(const bf8v*)(AL + (long)br[nt]*128 + kc + q*8);
#pragma unroll
        for (int mt = 0; mt < 4; ++mt)
#pragma unroll
            for (int nt = 0; nt < 4; ++nt)
                acc[mt][nt] = __builtin_amdgcn_mfma_f32_16x16x32_bf16(a[mt], b[nt], acc[mt][nt], 0, 0, 0);
    }
    float lsum = 0.f;
#pragma unroll
    for (int mt = 0; mt < 4; ++mt)
#pragma unroll
    for (int nt = 0; nt < 4; ++nt) {
        int n = bn + nt*16 + ln;
        if (n >= N) continue;
#pragma unroll
        for (int r = 0; r < 4; ++r) {
            int m = bm + mt*16 + q*4 + r;
            float s = acc[mt][nt][r];
            float e = __expf(-fabsf(s));
            float inv = 1.f / (1.f + e);
            __builtin_nontemporal_store((s >= 0.f) ? inv : e * inv, &out[(long)m*N + n]);
            lsum += fmaxf(s, 0.f) + __logf(1.f + e);
        }
    }
#pragma unroll
    for (int off = 32; off; off >>= 1) lsum += __shfl_xor(lsum, off);
    __shared__ float red[4];
    if (lane == 0) red[wave] = lsum;
    __syncthreads();
    if (tid == 0) atomicAdd(sp_acc, red[0] + red[1] + red[2] + red[3]);
}

// ---------------------------------------------------------------- per-b score_[b, obj_b], accumulate -s
__global__ __launch_bounds__(64) void objdot_k(
    const u16* __restrict__ V, const u16* __restrict__ AL, const int* __restrict__ trip,
    float* __restrict__ obj_acc)
{
    int b = blockIdx.x, lane = threadIdx.x;
    int obj = trip[b*3 + 2];
    const u16* v = V + (long)b*128;
    const u16* a = AL + (long)obj*128;
    float s = 0.f;
    for (int k = lane; k < 128; k += 64) s += bf2f(v[k]) * bf2f(a[k]);
    for (int off = 32; off; off >>= 1) s += __shfl_down(s, off);
    if (lane == 0) atomicAdd(obj_acc, -s);
}

// ---------------------------------------------------------------- finalize scalars
__global__ void final_k(const float* __restrict__ acc, float* __restrict__ out)
{
    out[20480000] = acc[0] / (1024.f * 128.f);
    out[20480001] = (acc[1] + acc[2]) / (1024.f * 20000.f);
}

// ================================================================ host
extern "C" void kernel_launch(void* const* d_in, const int* in_sizes, int n_in,
                              void* d_out, int out_size, void* d_ws, size_t ws_size,
                              hipStream_t stream)
{
    const float* ent  = (const float*)d_in[0];
    const float* rel  = (const float*)d_in[1];
    const float* Wn   = (const float*)d_in[2];
    const float* Wl   = (const float*)d_in[3];
    const float* We   = (const float*)d_in[4];
    const float* wih  = (const float*)d_in[5];
    const float* whh  = (const float*)d_in[6];
    const float* b_ih = (const float*)d_in[7];
    const float* b_hh = (const float*)d_in[8];
    const float* Wm1  = (const float*)d_in[9];
    const float* bm1  = (const float*)d_in[10];
    const float* Wm2  = (const float*)d_in[11];
    const float* bm2  = (const float*)d_in[12];
    const float* Wh1  = (const float*)d_in[13];
    const float* bh1  = (const float*)d_in[14];
    const float* Wh2  = (const float*)d_in[15];
    const float* bh2  = (const float*)d_in[16];
    const float* Wal  = (const float*)d_in[17];
    const float* bal  = (const float*)d_in[18];
    const float* Wat  = (const float*)d_in[19];
    const float* bat  = (const float*)d_in[20];
    const float* part = (const float*)d_in[21];
    const int* esrc   = (const int*)d_in[22];
    const int* edst   = (const int*)d_in[23];
    const int* etyp   = (const int*)d_in[24];
    const int* trip   = (const int*)d_in[25];
    float* out = (float*)d_out;
    const int E = in_sizes[22];

    char* ws = (char*)d_ws;
    size_t off = 0;
    auto alloc = [&](size_t bytes) { size_t o = off; off = (off + bytes + 255) & ~(size_t)255; return o; };

    // zeroed region first (one memset)
    size_t o_acc   = alloc(256);                  // [0]=match [1]=softplus [2]=obj
    size_t o_hist  = alloc(20000 * 4);
    size_t o_mapT  = alloc(128 * 480 * 2);
    size_t zend = off;
    // non-zeroed
    size_t o_starts= alloc(20004 * 4);
    size_t o_cur   = alloc(20000 * 4);
    size_t o_spack = alloc((size_t)E * 8);
    size_t o_entb  = alloc((size_t)20000 * 128 * 2);
    size_t o_acat  = alloc((size_t)20000 * 384 * 2);
    size_t o_pre   = alloc((size_t)20000 * 128 * 2);
    size_t o_aln   = alloc((size_t)20000 * 128 * 2);
    size_t o_bcat  = alloc(128 * 384 * 2);
    size_t o_wih   = alloc(384 * 128 * 2);
    size_t o_whh   = alloc(384 * 128 * 2);
    size_t o_m1    = alloc(256 * 128 * 2);
    size_t o_m2    = alloc(128 * 256 * 2);
    size_t o_h1    = alloc(128 * 128 * 2);
    size_t o_h2    = alloc(128 * 128 * 2);
    size_t o_at    = alloc(128 * 128 * 2);
    size_t o_al    = alloc(128 * 128 * 2);
    size_t o_rel   = alloc(460 * 128 * 2);
    size_t o_t1    = alloc(460 * 256 * 2);
    size_t o_map   = alloc(460 * 128 * 2);
    size_t o_qrel  = alloc(1024 * 128 * 2);
    size_t o_atq   = alloc(1024 * 128 * 2);
    size_t o_th1   = alloc(1024 * 128 * 2);
    size_t o_pred  = alloc(1024 * 128 * 4);
    size_t o_amat  = alloc((size_t)1024 * 460 * 4);
    size_t o_xat   = alloc((size_t)8192 * 480 * 2);
    size_t o_X     = alloc((size_t)9216 * 128 * 2);
    size_t o_gi    = alloc((size_t)9216 * 384 * 4);
    size_t o_subl  = alloc(1024 * 128 * 4);
    size_t o_gh2   = alloc(1024 * 128 * 4);
    size_t o_V     = alloc(1024 * 128 * 2);

    float* accp  = (float*)(ws + o_acc);
    int* histp   = (int*)(ws + o_hist);
    u16* mapT    = (u16*)(ws + o_mapT);
    int* startsp = (int*)(ws + o_starts);
    int* curp    = (int*)(ws + o_cur);
    int2* spack  = (int2*)(ws + o_spack);
    u16* entb    = (u16*)(ws + o_entb);
    u16* acat    = (u16*)(ws + o_acat);
    u16* preb    = (u16*)(ws + o_pre);
    u16* alnb    = (u16*)(ws + o_aln);
    u16* bcat    = (u16*)(ws + o_bcat);
    u16* wihb    = (u16*)(ws + o_wih);
    u16* whhb    = (u16*)(ws + o_whh);
    u16* m1b     = (u16*)(ws + o_m1);
    u16* m2b     = (u16*)(ws + o_m2);
    u16* h1b     = (u16*)(ws + o_h1);
    u16* h2b     = (u16*)(ws + o_h2);
    u16* atb     = (u16*)(ws + o_at);
    u16* alb     = (u16*)(ws + o_al);
    u16* relb    = (u16*)(ws + o_rel);
    u16* t1b     = (u16*)(ws + o_t1);
    u16* mapb    = (u16*)(ws + o_map);
    u16* qrelb   = (u16*)(ws + o_qrel);
    u16* atqb    = (u16*)(ws + o_atq);
    u16* th1b    = (u16*)(ws + o_th1);
    float* predf = (float*)(ws + o_pred);
    float* amat  = (float*)(ws + o_amat);
    u16* xat     = (u16*)(ws + o_xat);
    u16* Xb      = (u16*)(ws + o_X);
    float* gif   = (float*)(ws + o_gi);
    float* subl  = (float*)(ws + o_subl);
    float* gh2f  = (float*)(ws + o_gh2);
    u16* Vb      = (u16*)(ws + o_V);

    hipMemsetAsync(ws, 0, zend, stream);

    prep_k<<<1318, 256, 0, stream>>>(Wn, Wl, We, wih, whh, Wm1, Wm2, Wh1, Wh2, Wat, Wal, rel,
                                     bcat, wihb, whhb, m1b, m2b, h1b, h2b, atb, alb, relb);
    entcast_k<<<10000, 256, 0, stream>>>(ent, entb);

    // counting sort by dst, then segmented sum (no float atomics)
    int eb = (E + 255) / 256;
    hist_k<<<eb, 256, 0, stream>>>(edst, histp, E);
    scan_k<<<1, 1024, 0, stream>>>(histp, startsp, curp);
    scatter_k<<<eb, 256, 0, stream>>>(esrc, edst, etyp, curp, spack, E);
    agg_acat_k<<<20000, 64, 0, stream>>>(spack, startsp, (const u32*)entb, (const u32*)relb, (u32*)acat);

    // pre_emb = rrelu(A_cat @ Bcat^T)  [20000 x 128]
    gemm_nt<<<dim3(2, 313), 256, 0, stream>>>(acat, bcat, nullptr, nullptr, preb, nullptr, nullptr, nullptr,
                                              20000, 128, 384, 384, 384, 128, 0, 0, 0.f, 1);
    // aligned_all = pre_emb @ W_align^T + b_align
    gemm_nt<<<dim3(2, 313), 256, 0, stream>>>(preb, alb, bal, nullptr, alnb, nullptr, nullptr, nullptr,
                                              20000, 128, 128, 128, 128, 128, 0, 0, 0.f, 0);
    // t1 = rel_emb @ W_map1^T + b_map1  [460 x 256]
    gemm_nt<<<dim3(4, 8), 256, 0, stream>>>(relb, m1b, bm1, nullptr, t1b, nullptr, nullptr, nullptr,
                                            460, 256, 128, 128, 128, 256, 0, 0, 0.f, 0);
    // mapped_rel = t1 @ W_map2^T + b_map2  [460 x 128] (+ transposed copy, ldct=480)
    gemm_nt<<<dim3(2, 8), 256, 0, stream>>>(t1b, m2b, bm2, nullptr, mapb, mapT, nullptr, nullptr,
                                            460, 128, 256, 256, 256, 128, 480, 0, 0.f, 0);

    qrel_k<<<512, 256, 0, stream>>>(mapb, trip, qrelb, Xb);

    // attnq = q_rel @ W_attn^T + b_attn
    gemm_nt<<<dim3(2, 16), 256, 0, stream>>>(qrelb, atb, bat, nullptr, atqb, nullptr, nullptr, nullptr,
                                             1024, 128, 128, 128, 128, 128, 0, 0, 0.f, 0);
    // th1 = q_rel @ W_h1^T + b_h1
    gemm_nt<<<dim3(2, 16), 256, 0, stream>>>(qrelb, h1b, bh1, nullptr, th1b, nullptr, nullptr, nullptr,
                                             1024, 128, 128, 128, 128, 128, 0, 0, 0.f, 0);
    // predicted_hist = 0.1*(th1 @ W_h2^T + b_h2) + q_rel   (f32)
    gemm_nt<<<dim3(2, 16), 256, 0, stream>>>(th1b, h2b, bh2, predf, nullptr, nullptr, qrelb, nullptr,
                                             1024, 128, 128, 128, 128, 128, 0, 0, 0.1f, 0);
    // A = attnq @ mapped_rel^T  [1024 x 460] (f32)
    gemm_nt<<<dim3(8, 16), 256, 0, stream>>>(atqb, mapb, nullptr, amat, nullptr, nullptr, nullptr, nullptr,
                                             1024, 460, 128, 128, 128, 460, 0, 0, 0.f, 0);

    softmax_k<<<8192, 64, 0, stream>>>(amat, part, xat);

    // rel_path = attn @ mapped_rel  [8192 x 128] -> X rows 0..8191 (bf16)
    gemm_nt<<<dim3(2, 128), 256, 0, stream>>>(xat, mapT, nullptr, nullptr, Xb, nullptr, nullptr, nullptr,
                                              8192, 128, 480, 480, 480, 128, 0, 0, 0.f, 0);
    // gi = X @ w_ih^T + b_ih  [9216 x 384] (f32)
    gemm_nt<<<dim3(6, 144), 256, 0, stream>>>(Xb, wihb, b_ih, gif, nullptr, nullptr, nullptr, nullptr,
                                              9216, 384, 128, 128, 128, 384, 0, 0, 0.f, 0);
    // SubL = pre_emb[triples[:,0]] @ W_align^T + b_align  (f32)
    gemm_nt<<<dim3(2, 16), 256, 0, stream>>>(preb, alb, bal, subl, nullptr, nullptr, nullptr, trip,
                                             1024, 128, 128, 128, 128, 128, 0, 3, 0.f, 0);

    gru_k<<<256, 256, 0, stream>>>(gif, whhb, b_hh, predf, gh2f, accp + 0);

    vmul_k<<<512, 256, 0, stream>>>(subl, gh2f, Vb);

    score_k<<<dim3(157, 8), 256, 0, stream>>>(Vb, alnb, out, accp + 1, 20000);

    objdot_k<<<1024, 64, 0, stream>>>(Vb, alnb, trip, accp + 2);

    final_k<<<1, 1, 0, stream>>>(accp, out);

    (void)in_sizes; (void)n_in; (void)out_size; (void)ws_size;
}